// Round 1
// baseline (443.893 us; speedup 1.0000x reference)
//
#include <hip/hip_runtime.h>
#include <hip/hip_bf16.h>
#include <cstdint>
#include <cstddef>

#define B_ 512
#define L_ 200
#define D_ 128
#define M_ (B_*L_)
#define T_ 4

typedef short bf16x8 __attribute__((ext_vector_type(8)));
typedef unsigned short u16x8 __attribute__((ext_vector_type(8)));
typedef float f32x4 __attribute__((ext_vector_type(4)));

__device__ __forceinline__ float bf2f(unsigned short u){
  union { unsigned int i; float f; } c; c.i = ((unsigned int)u)<<16; return c.f;
}
__device__ __forceinline__ unsigned short f2bf(float f){
  union { float f; unsigned int i; } c; c.f = f;
  unsigned int r = c.i + 0x7FFFu + ((c.i>>16)&1u);
  return (unsigned short)(r>>16);
}
__device__ __forceinline__ float wsum(float v){
  #pragma unroll
  for (int m=1;m<64;m<<=1) v += __shfl_xor(v, m, 64);
  return v;
}

// ---------------------------------------------------------------------------
// Generic bf16 GEMM, C[M,N] = A[M,K] @ Bt[N,K]^T + bias, bf16 out.
// 128x128 tile, BK=32, 4 waves (2x2 of 64x64), 16x16x32 MFMA, 4x4 frags/wave.
// ---------------------------------------------------------------------------
__global__ __launch_bounds__(256)
void gemm_bt(const unsigned short* __restrict__ A, int lda,
             const unsigned short* __restrict__ Bt, int ldb,
             const float* __restrict__ bias,
             unsigned short* __restrict__ C, int ldc, int K)
{
  __shared__ int4 sA[512];   // [128 rows][32 bf16] = 8KB
  __shared__ int4 sB[512];
  const int tid = threadIdx.x;
  const int m0 = blockIdx.y * 128;
  const int n0 = blockIdx.x * 128;
  const int lane = tid & 63;
  const int w = tid >> 6;
  const int wr = (w>>1)*64, wc = (w&1)*64;

  f32x4 acc[4][4];
  #pragma unroll
  for (int i=0;i<4;i++)
    #pragma unroll
    for (int j=0;j<4;j++) acc[i][j] = (f32x4){0.f,0.f,0.f,0.f};

  const int c1 = tid, c2 = tid + 256;
  const int r1 = c1>>2, k1 = (c1&3)<<3;
  const int r2 = c2>>2, k2 = (c2&3)<<3;
  const short* sAs = (const short*)sA;
  const short* sBs = (const short*)sB;
  const int fr = lane & 15;          // frag row (A) / col (B)
  const int fk = (lane>>4)<<3;       // frag k offset

  for (int ks = 0; ks < K; ks += 32) {
    int4 a1 = *(const int4*)(A + (size_t)(m0 + r1)*lda + ks + k1);
    int4 a2 = *(const int4*)(A + (size_t)(m0 + r2)*lda + ks + k2);
    int4 b1 = *(const int4*)(Bt + (size_t)(n0 + r1)*ldb + ks + k1);
    int4 b2 = *(const int4*)(Bt + (size_t)(n0 + r2)*ldb + ks + k2);
    sA[c1] = a1; sA[c2] = a2; sB[c1] = b1; sB[c2] = b2;
    __syncthreads();
    bf16x8 af[4], bfr[4];
    #pragma unroll
    for (int i=0;i<4;i++){
      af[i]  = *(const bf16x8*)(sAs + (wr + i*16 + fr)*32 + fk);
      bfr[i] = *(const bf16x8*)(sBs + (wc + i*16 + fr)*32 + fk);
    }
    #pragma unroll
    for (int i=0;i<4;i++)
      #pragma unroll
      for (int j=0;j<4;j++)
        acc[i][j] = __builtin_amdgcn_mfma_f32_16x16x32_bf16(af[i], bfr[j], acc[i][j], 0,0,0);
    __syncthreads();
  }

  const int orow = (lane>>4)<<2;   // C/D: col=lane&15, row=(lane>>4)*4+reg
  #pragma unroll
  for (int i=0;i<4;i++){
    #pragma unroll
    for (int j=0;j<4;j++){
      const int gn = n0 + wc + j*16 + fr;
      const float bv = bias ? bias[gn] : 0.f;
      #pragma unroll
      for (int v=0;v<4;v++){
        const int gm = m0 + wr + i*16 + orow + v;
        C[(size_t)gm*ldc + gn] = f2bf(acc[i][j][v] + bv);
      }
    }
  }
}

// ---------------------------------------------------------------------------
// Weight prep: fp32 -> bf16 packed matrices + fused biases
// ---------------------------------------------------------------------------
__global__ __launch_bounds__(256)
void k_prep(const float* __restrict__ W_in, const float* __restrict__ b_in,
            const float* __restrict__ W_out, const float* __restrict__ b_out,
            const float* __restrict__ w_ih, const float* __restrict__ w_hh,
            const float* __restrict__ b_ih, const float* __restrict__ b_hh,
            const float* __restrict__ W1, const float* __restrict__ W2,
            unsigned short* __restrict__ wE, unsigned short* __restrict__ wG,
            unsigned short* __restrict__ w1b, unsigned short* __restrict__ w2b,
            float* __restrict__ biasE, float* __restrict__ biasG)
{
  const int i = blockIdx.x*256 + threadIdx.x;
  if (i < 32768) {                       // wE [256][128] = [W_in; W_out]
    int n = i>>7, k = i&127;
    float v = (n<128) ? W_in[n*128+k] : W_out[(n-128)*128+k];
    wE[i] = f2bf(v);
  }
  if (i < 196608) {                      // wG [512][384]
    int n = i/384, k = i - n*384;
    float v;
    if (n < 256)      v = (k<256) ? w_ih[n*256+k] : w_hh[n*128 + (k-256)];
    else if (n < 384) v = (k<256) ? w_ih[n*256+k] : 0.f;       // i_n
    else              v = (k<256) ? 0.f : w_hh[(n-128)*128 + (k-256)]; // h_n
    wG[i] = f2bf(v);
  }
  if (i < 16384) { w1b[i] = f2bf(W1[i]); w2b[i] = f2bf(W2[i]); }
  if (i < 256) biasE[i] = (i<128) ? b_in[i] : b_out[i-128];
  if (i < 512) {
    float v;
    if (i < 256)      v = b_ih[i] + b_hh[i];
    else if (i < 384) v = b_ih[i];
    else              v = b_hh[i-128];
    biasG[i] = v;
  }
}

// ---------------------------------------------------------------------------
// Embedding gather: X2[:,256:384] = bf16(item_emb[items])
// ---------------------------------------------------------------------------
__global__ __launch_bounds__(256)
void k_embed(const int* __restrict__ items, const float* __restrict__ emb,
             unsigned short* __restrict__ X2)
{
  const int idx = blockIdx.x*256 + threadIdx.x;  // M*32 threads, 4 dims each
  const int row = idx >> 5, d4 = (idx & 31) << 2;
  const int it = items[row];
  const float4 v = *(const float4*)(emb + (size_t)it*128 + d4);
  ushort4 o; o.x=f2bf(v.x); o.y=f2bf(v.y); o.z=f2bf(v.z); o.w=f2bf(v.w);
  *(ushort4*)(X2 + (size_t)row*384 + 256 + d4) = o;
}

// ---------------------------------------------------------------------------
// Graph aggregation, one block per batch. Reconstructs uA from alias/len
// (deduplicated edges via bitmaps, no atomics -> deterministic).
// X2[:,0:128] = input_in + b_iah ; X2[:,128:256] = input_out + b_ioh
// ---------------------------------------------------------------------------
__global__ __launch_bounds__(256)
void k_agg(const int* __restrict__ alias, const int* __restrict__ lens,
           const unsigned short* __restrict__ E, unsigned short* __restrict__ X2,
           const float* __restrict__ b_iah, const float* __restrict__ b_ioh)
{
  const int b = blockIdx.x, tid = threadIdx.x;
  __shared__ int al[L_];
  __shared__ unsigned bmIn[L_*8], bmOut[L_*8];
  if (tid < L_) al[tid] = alias[b*L_ + tid];
  for (int i=tid; i<L_*8; i+=256){ bmIn[i]=0u; bmOut[i]=0u; }
  __syncthreads();
  const int len = lens[b];
  if (tid < L_) {
    const int c = tid;
    for (int t=0; t<len-1; ++t) {
      if (al[t+1]==c) bmIn[c*8 + (al[t]>>5)]   |= (1u<<(al[t]&31));
      if (al[t]==c)   bmOut[c*8 + (al[t+1]>>5)] |= (1u<<(al[t+1]&31));
    }
  }
  __syncthreads();
  const int g = tid >> 7, d = tid & 127;
  const float bi = b_iah[d], bo = b_ioh[d];
  for (int base=0; base<L_; base+=2) {
    const int i = base + g;
    float si=0.f, so=0.f; int ci=0, co=0;
    #pragma unroll
    for (int wd=0; wd<8; ++wd) {
      unsigned word = bmIn[i*8+wd];
      while (word) { int j = __ffs(word)-1; word &= word-1u;
        si += bf2f(E[((size_t)(b*L_ + wd*32 + j))*256 + d]); ci++; }
      word = bmOut[i*8+wd];
      while (word) { int j = __ffs(word)-1; word &= word-1u;
        so += bf2f(E[((size_t)(b*L_ + wd*32 + j))*256 + 128 + d]); co++; }
    }
    const float vin  = si / (float)(ci>0?ci:1) + bi;
    const float vout = so / (float)(co>0?co:1) + bo;
    unsigned short* xr = X2 + (size_t)(b*L_ + i)*384;
    xr[d] = f2bf(vin); xr[128+d] = f2bf(vout);
  }
}

// ---------------------------------------------------------------------------
// GRU cell elementwise: gates[M,512] = [i_r+h_r, i_i+h_i, i_n, h_n]
// ---------------------------------------------------------------------------
__global__ __launch_bounds__(256)
void k_gru(const unsigned short* __restrict__ gates,
           const unsigned short* __restrict__ X2,
           unsigned short* __restrict__ hidden)
{
  const int idx = blockIdx.x*256 + threadIdx.x;  // M*16 threads, 8 dims each
  const int row = idx >> 4, d8 = (idx & 15) << 3;
  const unsigned short* gr = gates + (size_t)row*512;
  const unsigned short* hr = X2 + (size_t)row*384 + 256;
  u16x8 g0v = *(const u16x8*)(gr + d8);
  u16x8 g1v = *(const u16x8*)(gr + 128 + d8);
  u16x8 g2v = *(const u16x8*)(gr + 256 + d8);
  u16x8 g3v = *(const u16x8*)(gr + 384 + d8);
  u16x8 hv  = *(const u16x8*)(hr + d8);
  u16x8 o;
  #pragma unroll
  for (int q=0;q<8;q++){
    float r = 1.f/(1.f+__expf(-bf2f(g0v[q])));
    float z = 1.f/(1.f+__expf(-bf2f(g1v[q])));
    float x = bf2f(g2v[q]) + r*bf2f(g3v[q]);
    float n = 1.f - 2.f/(__expf(2.f*x)+1.f);   // tanh
    o[q] = f2bf((1.f-z)*bf2f(hv[q]) + z*n);
  }
  *(u16x8*)(hidden + (size_t)row*128 + d8) = o;
}

// ---------------------------------------------------------------------------
// seq_hidden gather + ht extraction
// ---------------------------------------------------------------------------
__global__ __launch_bounds__(256)
void k_gather(const unsigned short* __restrict__ hidden,
              const int* __restrict__ alias, const int* __restrict__ lens,
              unsigned short* __restrict__ seqh, unsigned short* __restrict__ htb)
{
  const int idx = blockIdx.x*256 + threadIdx.x;  // M*16
  const int row = idx >> 4, d8 = (idx & 15) << 3;
  const int b = row / L_, l = row - b*L_;
  const int alv = alias[row];
  u16x8 v = *(const u16x8*)(hidden + (size_t)(b*L_ + alv)*128 + d8);
  *(u16x8*)(seqh + (size_t)row*128 + d8) = v;
  if (l == lens[b]-1) *(u16x8*)(htb + (size_t)b*128 + d8) = v;
}

// ---------------------------------------------------------------------------
// LN + LIF(4 steps, constant input) + alpha = Qs.W3 + masked sum -> a[T,B,D]
// One block per batch; one wave per row (lane handles dims d and d+64).
// ---------------------------------------------------------------------------
__global__ __launch_bounds__(256)
void k_attn(const unsigned short* __restrict__ Q0, const unsigned short* __restrict__ htW1,
            const unsigned short* __restrict__ seqh, const int* __restrict__ lens,
            const float* __restrict__ g_q, const float* __restrict__ beta_q,
            const float* __restrict__ W3, float* __restrict__ a_out)
{
  const int b = blockIdx.x, tid = threadIdx.x;
  const int w = tid>>6, lane = tid&63;
  __shared__ float a_acc[4][T_][128];
  for (int i=tid; i<4*T_*128; i+=256) ((float*)a_acc)[i] = 0.f;
  const float h0 = bf2f(htW1[b*128 + lane]), h1 = bf2f(htW1[b*128 + lane + 64]);
  const float gq0 = g_q[lane], gq1 = g_q[lane+64];
  const float bq0 = beta_q[lane], bq1 = beta_q[lane+64];
  const float w30 = W3[lane], w31 = W3[lane+64];
  const int len = lens[b];
  __syncthreads();
  for (int l = w; l < L_; l += 4) {
    const size_t row = (size_t)b*L_ + l;
    const float q0 = bf2f(Q0[row*128 + lane]) + h0;
    const float q1 = bf2f(Q0[row*128 + lane + 64]) + h1;
    const float m = wsum(q0+q1) * (1.f/128.f);
    const float d0 = q0-m, d1 = q1-m;
    const float var = wsum(d0*d0 + d1*d1) * (1.f/128.f);
    const float inv = rsqrtf(var + 1e-5f);
    const float x0 = d0*inv*gq0 + bq0;
    const float x1 = d1*inv*gq1 + bq1;
    const float sh0 = bf2f(seqh[row*128+lane]), sh1 = bf2f(seqh[row*128+lane+64]);
    const bool active = (l < len);
    float v0=0.f, v1=0.f;
    #pragma unroll
    for (int t=0;t<T_;t++){
      v0 = 0.5f*(v0+x0); v1 = 0.5f*(v1+x1);
      const float s0 = (v0>=1.f)?1.f:0.f, s1 = (v1>=1.f)?1.f:0.f;
      v0 -= s0*v0; v1 -= s1*v1;
      const float alpha = wsum(s0*w30 + s1*w31);
      if (active){ a_acc[w][t][lane] += alpha*sh0; a_acc[w][t][lane+64] += alpha*sh1; }
    }
  }
  __syncthreads();
  for (int i=tid; i<T_*128; i+=256){
    const int t = i>>7, d = i&127;
    const float s = a_acc[0][t][d]+a_acc[1][t][d]+a_acc[2][t][d]+a_acc[3][t][d];
    a_out[((size_t)t*B_ + b)*128 + d] = s;
  }
}

// ---------------------------------------------------------------------------
// Final: sh=[a,ht], LIF over T (sequential), LN(binary spikes), @Wt.T, mean_T
// One block per batch, 256 threads (= 2D dims).
// ---------------------------------------------------------------------------
__global__ __launch_bounds__(256)
void k_final(const float* __restrict__ a_in, const unsigned short* __restrict__ hidden,
             const int* __restrict__ alias, const int* __restrict__ lens,
             const float* __restrict__ g_sh, const float* __restrict__ beta_sh,
             const float* __restrict__ Wt, float* __restrict__ out)
{
  const int b = blockIdx.x, tid = threadIdx.x;
  const int w = tid>>6, lane = tid&63;
  __shared__ float yl[T_][256];
  __shared__ float part[T_][4];
  const int len = lens[b];
  float xh = 0.f;
  if (tid >= 128) {
    const int al = alias[b*L_ + len - 1];
    xh = bf2f(hidden[((size_t)(b*L_ + al))*128 + (tid-128)]);
  }
  float v = 0.f; float sp[T_];
  #pragma unroll
  for (int t=0;t<T_;t++){
    const float x = (tid<128) ? a_in[((size_t)t*B_ + b)*128 + tid] : xh;
    v = 0.5f*(v + x);
    const float s = (v>=1.f)?1.f:0.f;
    v -= s*v;
    sp[t] = s;
  }
  #pragma unroll
  for (int t=0;t<T_;t++){
    const float r = wsum(sp[t]);
    if (lane==0) part[t][w] = r;
  }
  __syncthreads();
  #pragma unroll
  for (int t=0;t<T_;t++){
    const float k = part[t][0]+part[t][1]+part[t][2]+part[t][3];
    const float mean = k * (1.f/256.f);
    const float varr = mean - mean*mean;   // spikes are binary: E[x^2]=E[x]
    const float inv = rsqrtf(varr + 1e-5f);
    yl[t][tid] = (sp[t]-mean)*inv*g_sh[tid] + beta_sh[tid];
  }
  __syncthreads();
  if (tid < 128) {
    float acc = 0.f;
    const float* wr = Wt + (size_t)tid*256;
    for (int k=0;k<256;k++)
      acc += wr[k]*(yl[0][k]+yl[1][k]+yl[2][k]+yl[3][k]);
    out[(size_t)b*128 + tid] = acc*0.25f;
  }
}

// ---------------------------------------------------------------------------
extern "C" void kernel_launch(void* const* d_in, const int* in_sizes, int n_in,
                              void* d_out, int out_size, void* d_ws, size_t ws_size,
                              hipStream_t stream)
{
  const int*   alias  = (const int*)d_in[1];
  const int*   items  = (const int*)d_in[2];
  const int*   lens   = (const int*)d_in[4];
  const float* emb    = (const float*)d_in[5];
  const float* W_in   = (const float*)d_in[6];
  const float* b_in   = (const float*)d_in[7];
  const float* W_out  = (const float*)d_in[8];
  const float* b_out  = (const float*)d_in[9];
  const float* w_ih   = (const float*)d_in[10];
  const float* w_hh   = (const float*)d_in[11];
  const float* b_ih   = (const float*)d_in[12];
  const float* b_hh   = (const float*)d_in[13];
  const float* b_iah  = (const float*)d_in[14];
  const float* b_ioh  = (const float*)d_in[15];
  const float* W1     = (const float*)d_in[16];
  const float* W2     = (const float*)d_in[17];
  const float* W3     = (const float*)d_in[18];
  const float* Wt     = (const float*)d_in[19];
  const float* g_q    = (const float*)d_in[20];
  const float* beta_q = (const float*)d_in[21];
  const float* g_sh   = (const float*)d_in[22];
  const float* beta_sh= (const float*)d_in[23];

  char* ws = (char*)d_ws;
  size_t off = 0;
  auto alloc = [&](size_t bytes)->void* {
    void* p = ws + off; off += (bytes + 255) & ~(size_t)255; return p;
  };
  unsigned short* X2    = (unsigned short*)alloc((size_t)M_*384*2);   // [in|out|hidden]
  unsigned short* Eg    = (unsigned short*)alloc((size_t)M_*512*2);   // E -> gates -> Q0 (reused)
  unsigned short* hidden= (unsigned short*)alloc((size_t)M_*128*2);
  unsigned short* seqh  = (unsigned short*)alloc((size_t)M_*128*2);
  unsigned short* htb   = (unsigned short*)alloc((size_t)B_*128*2);
  unsigned short* htW1  = (unsigned short*)alloc((size_t)B_*128*2);
  float*          a_buf = (float*)alloc((size_t)T_*B_*128*4);
  unsigned short* wE    = (unsigned short*)alloc(32768*2);
  unsigned short* wG    = (unsigned short*)alloc((size_t)196608*2);
  unsigned short* w1b   = (unsigned short*)alloc(16384*2);
  unsigned short* w2b   = (unsigned short*)alloc(16384*2);
  float*          biasE = (float*)alloc(256*4);
  float*          biasG = (float*)alloc(512*4);
  if (off > ws_size) return;  // workspace too small -> visible as validation failure

  unsigned short* E     = Eg;            // [M,256]
  unsigned short* gates = Eg;            // [M,512] (E dead)
  unsigned short* Q0    = Eg;            // [M,128] (gates dead)

  k_prep<<<768,256,0,stream>>>(W_in,b_in,W_out,b_out,w_ih,w_hh,b_ih,b_hh,W1,W2,
                               wE,wG,w1b,w2b,biasE,biasG);
  k_embed<<<M_*32/256,256,0,stream>>>(items, emb, X2);
  gemm_bt<<<dim3(2,800),256,0,stream>>>(X2+256, 384, wE, 128, biasE, E, 256, 128);
  k_agg<<<B_,256,0,stream>>>(alias, lens, E, X2, b_iah, b_ioh);
  gemm_bt<<<dim3(4,800),256,0,stream>>>(X2, 384, wG, 384, biasG, gates, 512, 384);
  k_gru<<<M_*16/256,256,0,stream>>>(gates, X2, hidden);
  k_gather<<<M_*16/256,256,0,stream>>>(hidden, alias, lens, seqh, htb);
  gemm_bt<<<dim3(1,4),256,0,stream>>>(htb, 128, w1b, 128, nullptr, htW1, 128, 128);
  gemm_bt<<<dim3(1,800),256,0,stream>>>(seqh, 128, w2b, 128, nullptr, Q0, 128, 128);
  k_attn<<<B_,256,0,stream>>>(Q0, htW1, seqh, lens, g_q, beta_q, W3, a_buf);
  k_final<<<B_,256,0,stream>>>(a_buf, hidden, alias, lens, g_sh, beta_sh, Wt, (float*)d_out);
}

// Round 2
// 291.320 us; speedup vs baseline: 1.5237x; 1.5237x over previous
//
#include <hip/hip_runtime.h>
#include <hip/hip_bf16.h>
#include <cstdint>
#include <cstddef>

#define B_ 512
#define L_ 200
#define D_ 128
#define M_ (B_*L_)
#define T_ 4

typedef short bf16x8 __attribute__((ext_vector_type(8)));
typedef unsigned short u16x8 __attribute__((ext_vector_type(8)));
typedef float f32x4 __attribute__((ext_vector_type(4)));

__device__ __forceinline__ float bf2f(unsigned short u){
  union { unsigned int i; float f; } c; c.i = ((unsigned int)u)<<16; return c.f;
}
__device__ __forceinline__ unsigned short f2bf(float f){
  union { float f; unsigned int i; } c; c.f = f;
  unsigned int r = c.i + 0x7FFFu + ((c.i>>16)&1u);
  return (unsigned short)(r>>16);
}
__device__ __forceinline__ float wsum(float v){
  #pragma unroll
  for (int m=1;m<64;m<<=1) v += __shfl_xor(v, m, 64);
  return v;
}
__device__ __forceinline__ void gload_lds16(const void* g, void* l){
  __builtin_amdgcn_global_load_lds(
      (const __attribute__((address_space(1))) void*)g,
      (__attribute__((address_space(3))) void*)l, 16, 0, 0);
}

// ---------------------------------------------------------------------------
// Generic bf16 GEMM, C[M,N] = A[M,K] @ Bt[N,K]^T + bias, bf16 out.
// 128x128 tile, BK=32, 4 waves (2x2 of 64x64), 16x16x32 MFMA, 4x4 frags/wave.
// Staging via global_load_lds width=16 (LDS dst is wave-uniform base+lane*16).
// ---------------------------------------------------------------------------
__global__ __launch_bounds__(256)
void gemm_bt(const unsigned short* __restrict__ A, int lda,
             const unsigned short* __restrict__ Bt, int ldb,
             const float* __restrict__ bias,
             unsigned short* __restrict__ C, int ldc, int K)
{
  __shared__ int4 sA[512];   // [128 rows][32 bf16] = 8KB
  __shared__ int4 sB[512];
  const int tid = threadIdx.x;
  const int m0 = blockIdx.y * 128;
  const int n0 = blockIdx.x * 128;
  const int lane = tid & 63;
  const int w = tid >> 6;
  const int wr = (w>>1)*64, wc = (w&1)*64;

  f32x4 acc[4][4];
  #pragma unroll
  for (int i=0;i<4;i++)
    #pragma unroll
    for (int j=0;j<4;j++) acc[i][j] = (f32x4){0.f,0.f,0.f,0.f};

  const int c1 = tid, c2 = tid + 256;
  const int r1 = c1>>2, k1 = (c1&3)<<3;
  const int r2 = c2>>2, k2 = (c2&3)<<3;
  const short* sAs = (const short*)sA;
  const short* sBs = (const short*)sB;
  const int fr = lane & 15;          // frag row (A) / col (B)
  const int fk = (lane>>4)<<3;       // frag k offset

  for (int ks = 0; ks < K; ks += 32) {
    gload_lds16(A  + (size_t)(m0 + r1)*lda + ks + k1, &sA[c1]);
    gload_lds16(A  + (size_t)(m0 + r2)*lda + ks + k2, &sA[c2]);
    gload_lds16(Bt + (size_t)(n0 + r1)*ldb + ks + k1, &sB[c1]);
    gload_lds16(Bt + (size_t)(n0 + r2)*ldb + ks + k2, &sB[c2]);
    __syncthreads();
    bf16x8 af[4], bfr[4];
    #pragma unroll
    for (int i=0;i<4;i++){
      af[i]  = *(const bf16x8*)(sAs + (wr + i*16 + fr)*32 + fk);
      bfr[i] = *(const bf16x8*)(sBs + (wc + i*16 + fr)*32 + fk);
    }
    #pragma unroll
    for (int i=0;i<4;i++)
      #pragma unroll
      for (int j=0;j<4;j++)
        acc[i][j] = __builtin_amdgcn_mfma_f32_16x16x32_bf16(af[i], bfr[j], acc[i][j], 0,0,0);
    __syncthreads();
  }

  const int orow = (lane>>4)<<2;   // C/D: col=lane&15, row=(lane>>4)*4+reg
  #pragma unroll
  for (int i=0;i<4;i++){
    #pragma unroll
    for (int j=0;j<4;j++){
      const int gn = n0 + wc + j*16 + fr;
      const float bv = bias ? bias[gn] : 0.f;
      #pragma unroll
      for (int v=0;v<4;v++){
        const int gm = m0 + wr + i*16 + orow + v;
        C[(size_t)gm*ldc + gn] = f2bf(acc[i][j][v] + bv);
      }
    }
  }
}

// ---------------------------------------------------------------------------
// Weight prep: fp32 -> bf16 packed matrices + fused biases
// ---------------------------------------------------------------------------
__global__ __launch_bounds__(256)
void k_prep(const float* __restrict__ W_in, const float* __restrict__ b_in,
            const float* __restrict__ W_out, const float* __restrict__ b_out,
            const float* __restrict__ w_ih, const float* __restrict__ w_hh,
            const float* __restrict__ b_ih, const float* __restrict__ b_hh,
            const float* __restrict__ W1, const float* __restrict__ W2,
            unsigned short* __restrict__ wE, unsigned short* __restrict__ wG,
            unsigned short* __restrict__ w1b, unsigned short* __restrict__ w2b,
            float* __restrict__ biasE, float* __restrict__ biasG)
{
  const int i = blockIdx.x*256 + threadIdx.x;
  if (i < 32768) {                       // wE [256][128] = [W_in; W_out]
    int n = i>>7, k = i&127;
    float v = (n<128) ? W_in[n*128+k] : W_out[(n-128)*128+k];
    wE[i] = f2bf(v);
  }
  if (i < 196608) {                      // wG [512][384]
    int n = i/384, k = i - n*384;
    float v;
    if (n < 256)      v = (k<256) ? w_ih[n*256+k] : w_hh[n*128 + (k-256)];
    else if (n < 384) v = (k<256) ? w_ih[n*256+k] : 0.f;       // i_n
    else              v = (k<256) ? 0.f : w_hh[(n-128)*128 + (k-256)]; // h_n
    wG[i] = f2bf(v);
  }
  if (i < 16384) { w1b[i] = f2bf(W1[i]); w2b[i] = f2bf(W2[i]); }
  if (i < 256) biasE[i] = (i<128) ? b_in[i] : b_out[i-128];
  if (i < 512) {
    float v;
    if (i < 256)      v = b_ih[i] + b_hh[i];
    else if (i < 384) v = b_ih[i];
    else              v = b_hh[i-128];
    biasG[i] = v;
  }
}

// ---------------------------------------------------------------------------
// Embedding gather: X2[:,256:384] = bf16(item_emb[items])
// ---------------------------------------------------------------------------
__global__ __launch_bounds__(256)
void k_embed(const int* __restrict__ items, const float* __restrict__ emb,
             unsigned short* __restrict__ X2)
{
  const int idx = blockIdx.x*256 + threadIdx.x;  // M*32 threads, 4 dims each
  const int row = idx >> 5, d4 = (idx & 31) << 2;
  const int it = items[row];
  const float4 v = *(const float4*)(emb + (size_t)it*128 + d4);
  ushort4 o; o.x=f2bf(v.x); o.y=f2bf(v.y); o.z=f2bf(v.z); o.w=f2bf(v.w);
  *(ushort4*)(X2 + (size_t)row*384 + 256 + d4) = o;
}

// ---------------------------------------------------------------------------
// Graph aggregation, one 1024-thread block per batch.
// Edge build: one thread per edge, LDS atomicOr into dedup bitmaps
// (OR is idempotent+commutative -> deterministic).
// Scan: 8 row-groups x 128 dims, 25 iterations.
// X2[:,0:128] = input_in + b_iah ; X2[:,128:256] = input_out + b_ioh
// ---------------------------------------------------------------------------
__global__ __launch_bounds__(1024)
void k_agg(const int* __restrict__ alias, const int* __restrict__ lens,
           const unsigned short* __restrict__ E, unsigned short* __restrict__ X2,
           const float* __restrict__ b_iah, const float* __restrict__ b_ioh)
{
  const int b = blockIdx.x, tid = threadIdx.x;
  __shared__ int al[L_];
  __shared__ unsigned bmIn[L_*8], bmOut[L_*8];
  if (tid < L_) al[tid] = alias[b*L_ + tid];
  for (int i=tid; i<L_*8; i+=1024){ bmIn[i]=0u; bmOut[i]=0u; }
  __syncthreads();
  const int len = lens[b];
  if (tid < len-1) {
    const int r = al[tid], c = al[tid+1];
    atomicOr(&bmIn[c*8 + (r>>5)],  1u<<(r&31));
    atomicOr(&bmOut[r*8 + (c>>5)], 1u<<(c&31));
  }
  __syncthreads();
  const int g = tid >> 7, d = tid & 127;   // 8 row-groups x 128 dims
  const float bi = b_iah[d], bo = b_ioh[d];
  for (int base=0; base<L_; base+=8) {
    const int i = base + g;
    float si=0.f, so=0.f; int ci=0, co=0;
    #pragma unroll
    for (int wd=0; wd<8; ++wd) {
      unsigned word = bmIn[i*8+wd];
      while (word) { int j = __ffs(word)-1; word &= word-1u;
        si += bf2f(E[((size_t)(b*L_ + wd*32 + j))*256 + d]); ci++; }
      word = bmOut[i*8+wd];
      while (word) { int j = __ffs(word)-1; word &= word-1u;
        so += bf2f(E[((size_t)(b*L_ + wd*32 + j))*256 + 128 + d]); co++; }
    }
    const float vin  = si / (float)(ci>0?ci:1) + bi;
    const float vout = so / (float)(co>0?co:1) + bo;
    unsigned short* xr = X2 + (size_t)(b*L_ + i)*384;
    xr[d] = f2bf(vin); xr[128+d] = f2bf(vout);
  }
}

// ---------------------------------------------------------------------------
// GRU cell elementwise: gates[M,512] = [i_r+h_r, i_i+h_i, i_n, h_n]
// ---------------------------------------------------------------------------
__global__ __launch_bounds__(256)
void k_gru(const unsigned short* __restrict__ gates,
           const unsigned short* __restrict__ X2,
           unsigned short* __restrict__ hidden)
{
  const int idx = blockIdx.x*256 + threadIdx.x;  // M*16 threads, 8 dims each
  const int row = idx >> 4, d8 = (idx & 15) << 3;
  const unsigned short* gr = gates + (size_t)row*512;
  const unsigned short* hr = X2 + (size_t)row*384 + 256;
  u16x8 g0v = *(const u16x8*)(gr + d8);
  u16x8 g1v = *(const u16x8*)(gr + 128 + d8);
  u16x8 g2v = *(const u16x8*)(gr + 256 + d8);
  u16x8 g3v = *(const u16x8*)(gr + 384 + d8);
  u16x8 hv  = *(const u16x8*)(hr + d8);
  u16x8 o;
  #pragma unroll
  for (int q=0;q<8;q++){
    float r = 1.f/(1.f+__expf(-bf2f(g0v[q])));
    float z = 1.f/(1.f+__expf(-bf2f(g1v[q])));
    float x = bf2f(g2v[q]) + r*bf2f(g3v[q]);
    float n = 1.f - 2.f/(__expf(2.f*x)+1.f);   // tanh
    o[q] = f2bf((1.f-z)*bf2f(hv[q]) + z*n);
  }
  *(u16x8*)(hidden + (size_t)row*128 + d8) = o;
}

// ---------------------------------------------------------------------------
// seq_hidden gather + ht extraction
// ---------------------------------------------------------------------------
__global__ __launch_bounds__(256)
void k_gather(const unsigned short* __restrict__ hidden,
              const int* __restrict__ alias, const int* __restrict__ lens,
              unsigned short* __restrict__ seqh, unsigned short* __restrict__ htb)
{
  const int idx = blockIdx.x*256 + threadIdx.x;  // M*16
  const int row = idx >> 4, d8 = (idx & 15) << 3;
  const int b = row / L_, l = row - b*L_;
  const int alv = alias[row];
  u16x8 v = *(const u16x8*)(hidden + (size_t)(b*L_ + alv)*128 + d8);
  *(u16x8*)(seqh + (size_t)row*128 + d8) = v;
  if (l == lens[b]-1) *(u16x8*)(htb + (size_t)b*128 + d8) = v;
}

// ---------------------------------------------------------------------------
// LN + LIF(4 steps, constant input) + alpha = Qs.W3 + masked sum -> a[T,B,D]
// One 1024-thread block per batch; one wave per row (lane: dims d, d+64).
// ---------------------------------------------------------------------------
__global__ __launch_bounds__(1024)
void k_attn(const unsigned short* __restrict__ Q0, const unsigned short* __restrict__ htW1,
            const unsigned short* __restrict__ seqh, const int* __restrict__ lens,
            const float* __restrict__ g_q, const float* __restrict__ beta_q,
            const float* __restrict__ W3, float* __restrict__ a_out)
{
  const int b = blockIdx.x, tid = threadIdx.x;
  const int w = tid>>6, lane = tid&63;
  __shared__ float a_acc[16][T_][128];
  for (int i=tid; i<16*T_*128; i+=1024) ((float*)a_acc)[i] = 0.f;
  const float h0 = bf2f(htW1[b*128 + lane]), h1 = bf2f(htW1[b*128 + lane + 64]);
  const float gq0 = g_q[lane], gq1 = g_q[lane+64];
  const float bq0 = beta_q[lane], bq1 = beta_q[lane+64];
  const float w30 = W3[lane], w31 = W3[lane+64];
  const int len = lens[b];
  __syncthreads();
  for (int l = w; l < L_; l += 16) {
    const size_t row = (size_t)b*L_ + l;
    const float q0 = bf2f(Q0[row*128 + lane]) + h0;
    const float q1 = bf2f(Q0[row*128 + lane + 64]) + h1;
    const float m = wsum(q0+q1) * (1.f/128.f);
    const float d0 = q0-m, d1 = q1-m;
    const float var = wsum(d0*d0 + d1*d1) * (1.f/128.f);
    const float inv = rsqrtf(var + 1e-5f);
    const float x0 = d0*inv*gq0 + bq0;
    const float x1 = d1*inv*gq1 + bq1;
    const float sh0 = bf2f(seqh[row*128+lane]), sh1 = bf2f(seqh[row*128+lane+64]);
    const bool active = (l < len);
    float v0=0.f, v1=0.f;
    #pragma unroll
    for (int t=0;t<T_;t++){
      v0 = 0.5f*(v0+x0); v1 = 0.5f*(v1+x1);
      const float s0 = (v0>=1.f)?1.f:0.f, s1 = (v1>=1.f)?1.f:0.f;
      v0 -= s0*v0; v1 -= s1*v1;
      const float alpha = wsum(s0*w30 + s1*w31);
      if (active){ a_acc[w][t][lane] += alpha*sh0; a_acc[w][t][lane+64] += alpha*sh1; }
    }
  }
  __syncthreads();
  for (int i=tid; i<T_*128; i+=1024){
    const int t = i>>7, d = i&127;
    float s = 0.f;
    #pragma unroll
    for (int p=0;p<16;p++) s += a_acc[p][t][d];
    a_out[((size_t)t*B_ + b)*128 + d] = s;
  }
}

// ---------------------------------------------------------------------------
// Final: sh=[a,ht], LIF over T (sequential), LN(binary spikes), @Wt.T, mean_T
// One block per batch, 256 threads (= 2D dims).
// ---------------------------------------------------------------------------
__global__ __launch_bounds__(256)
void k_final(const float* __restrict__ a_in, const unsigned short* __restrict__ hidden,
             const int* __restrict__ alias, const int* __restrict__ lens,
             const float* __restrict__ g_sh, const float* __restrict__ beta_sh,
             const float* __restrict__ Wt, float* __restrict__ out)
{
  const int b = blockIdx.x, tid = threadIdx.x;
  const int w = tid>>6, lane = tid&63;
  __shared__ float yl[T_][256];
  __shared__ float part[T_][4];
  const int len = lens[b];
  float xh = 0.f;
  if (tid >= 128) {
    const int al = alias[b*L_ + len - 1];
    xh = bf2f(hidden[((size_t)(b*L_ + al))*128 + (tid-128)]);
  }
  float v = 0.f; float sp[T_];
  #pragma unroll
  for (int t=0;t<T_;t++){
    const float x = (tid<128) ? a_in[((size_t)t*B_ + b)*128 + tid] : xh;
    v = 0.5f*(v + x);
    const float s = (v>=1.f)?1.f:0.f;
    v -= s*v;
    sp[t] = s;
  }
  #pragma unroll
  for (int t=0;t<T_;t++){
    const float r = wsum(sp[t]);
    if (lane==0) part[t][w] = r;
  }
  __syncthreads();
  #pragma unroll
  for (int t=0;t<T_;t++){
    const float k = part[t][0]+part[t][1]+part[t][2]+part[t][3];
    const float mean = k * (1.f/256.f);
    const float varr = mean - mean*mean;   // spikes are binary: E[x^2]=E[x]
    const float inv = rsqrtf(varr + 1e-5f);
    yl[t][tid] = (sp[t]-mean)*inv*g_sh[tid] + beta_sh[tid];
  }
  __syncthreads();
  if (tid < 128) {
    float acc = 0.f;
    const float* wr = Wt + (size_t)tid*256;
    for (int k=0;k<256;k++)
      acc += wr[k]*(yl[0][k]+yl[1][k]+yl[2][k]+yl[3][k]);
    out[(size_t)b*128 + tid] = acc*0.25f;
  }
}

// ---------------------------------------------------------------------------
extern "C" void kernel_launch(void* const* d_in, const int* in_sizes, int n_in,
                              void* d_out, int out_size, void* d_ws, size_t ws_size,
                              hipStream_t stream)
{
  const int*   alias  = (const int*)d_in[1];
  const int*   items  = (const int*)d_in[2];
  const int*   lens   = (const int*)d_in[4];
  const float* emb    = (const float*)d_in[5];
  const float* W_in   = (const float*)d_in[6];
  const float* b_in   = (const float*)d_in[7];
  const float* W_out  = (const float*)d_in[8];
  const float* b_out  = (const float*)d_in[9];
  const float* w_ih   = (const float*)d_in[10];
  const float* w_hh   = (const float*)d_in[11];
  const float* b_ih   = (const float*)d_in[12];
  const float* b_hh   = (const float*)d_in[13];
  const float* b_iah  = (const float*)d_in[14];
  const float* b_ioh  = (const float*)d_in[15];
  const float* W1     = (const float*)d_in[16];
  const float* W2     = (const float*)d_in[17];
  const float* W3     = (const float*)d_in[18];
  const float* Wt     = (const float*)d_in[19];
  const float* g_q    = (const float*)d_in[20];
  const float* beta_q = (const float*)d_in[21];
  const float* g_sh   = (const float*)d_in[22];
  const float* beta_sh= (const float*)d_in[23];

  char* ws = (char*)d_ws;
  size_t off = 0;
  auto alloc = [&](size_t bytes)->void* {
    void* p = ws + off; off += (bytes + 255) & ~(size_t)255; return p;
  };
  unsigned short* X2    = (unsigned short*)alloc((size_t)M_*384*2);   // [in|out|hidden]
  unsigned short* Eg    = (unsigned short*)alloc((size_t)M_*512*2);   // E -> gates -> Q0 (reused)
  unsigned short* hidden= (unsigned short*)alloc((size_t)M_*128*2);
  unsigned short* seqh  = (unsigned short*)alloc((size_t)M_*128*2);
  unsigned short* htb   = (unsigned short*)alloc((size_t)B_*128*2);
  unsigned short* htW1  = (unsigned short*)alloc((size_t)B_*128*2);
  float*          a_buf = (float*)alloc((size_t)T_*B_*128*4);
  unsigned short* wE    = (unsigned short*)alloc(32768*2);
  unsigned short* wG    = (unsigned short*)alloc((size_t)196608*2);
  unsigned short* w1b   = (unsigned short*)alloc(16384*2);
  unsigned short* w2b   = (unsigned short*)alloc(16384*2);
  float*          biasE = (float*)alloc(256*4);
  float*          biasG = (float*)alloc(512*4);
  if (off > ws_size) return;  // workspace too small -> visible as validation failure

  unsigned short* E     = Eg;            // [M,256]
  unsigned short* gates = Eg;            // [M,512] (E dead)
  unsigned short* Q0    = Eg;            // [M,128] (gates dead)

  k_prep<<<768,256,0,stream>>>(W_in,b_in,W_out,b_out,w_ih,w_hh,b_ih,b_hh,W1,W2,
                               wE,wG,w1b,w2b,biasE,biasG);
  k_embed<<<M_*32/256,256,0,stream>>>(items, emb, X2);
  gemm_bt<<<dim3(2,800),256,0,stream>>>(X2+256, 384, wE, 128, biasE, E, 256, 128);
  k_agg<<<B_,1024,0,stream>>>(alias, lens, E, X2, b_iah, b_ioh);
  gemm_bt<<<dim3(4,800),256,0,stream>>>(X2, 384, wG, 384, biasG, gates, 512, 384);
  k_gru<<<M_*16/256,256,0,stream>>>(gates, X2, hidden);
  k_gather<<<M_*16/256,256,0,stream>>>(hidden, alias, lens, seqh, htb);
  gemm_bt<<<dim3(1,4),256,0,stream>>>(htb, 128, w1b, 128, nullptr, htW1, 128, 128);
  gemm_bt<<<dim3(1,800),256,0,stream>>>(seqh, 128, w2b, 128, nullptr, Q0, 128, 128);
  k_attn<<<B_,1024,0,stream>>>(Q0, htW1, seqh, lens, g_q, beta_q, W3, a_buf);
  k_final<<<B_,256,0,stream>>>(a_buf, hidden, alias, lens, g_sh, beta_sh, Wt, (float*)d_out);
}

// Round 3
// 281.663 us; speedup vs baseline: 1.5760x; 1.0343x over previous
//
#include <hip/hip_runtime.h>
#include <hip/hip_bf16.h>
#include <cstdint>
#include <cstddef>

#define B_ 512
#define L_ 200
#define D_ 128
#define M_ (B_*L_)
#define T_ 4

typedef short bf16x8 __attribute__((ext_vector_type(8)));
typedef unsigned short u16x8 __attribute__((ext_vector_type(8)));
typedef float f32x4 __attribute__((ext_vector_type(4)));

__device__ __forceinline__ float bf2f(unsigned short u){
  union { unsigned int i; float f; } c; c.i = ((unsigned int)u)<<16; return c.f;
}
__device__ __forceinline__ unsigned short f2bf(float f){
  union { float f; unsigned int i; } c; c.f = f;
  unsigned int r = c.i + 0x7FFFu + ((c.i>>16)&1u);
  return (unsigned short)(r>>16);
}
__device__ __forceinline__ float wsum(float v){
  #pragma unroll
  for (int m=1;m<64;m<<=1) v += __shfl_xor(v, m, 64);
  return v;
}
__device__ __forceinline__ void gload_lds16(const void* g, void* l){
  __builtin_amdgcn_global_load_lds(
      (const __attribute__((address_space(1))) void*)g,
      (__attribute__((address_space(3))) void*)l, 16, 0, 0);
}

// ---------------------------------------------------------------------------
// Generic bf16 GEMM, C[M,N] = A[M,K] @ Bt[N,K]^T + bias, bf16 out.
// 128x128 tile, BK=32, 4 waves, 16x16x32 MFMA, 4x4 frags/wave.
// LDS slot-swizzle: LDS[r][s] = global[r][s ^ ((r>>1)&3)] (16B slots),
// applied on the GLOBAL source (dest stays linear for global_load_lds)
// and inverted on the ds_read side. Kills the 8-way span conflicts.
// ---------------------------------------------------------------------------
__global__ __launch_bounds__(256)
void gemm_bt(const unsigned short* __restrict__ A, int lda,
             const unsigned short* __restrict__ Bt, int ldb,
             const float* __restrict__ bias,
             unsigned short* __restrict__ C, int ldc, int K)
{
  __shared__ int4 sA[512];   // [128 rows][32 bf16] = 8KB
  __shared__ int4 sB[512];
  const int tid = threadIdx.x;
  const int m0 = blockIdx.y * 128;
  const int n0 = blockIdx.x * 128;
  const int lane = tid & 63;
  const int w = tid >> 6;
  const int wr = (w>>1)*64, wc = (w&1)*64;

  f32x4 acc[4][4];
  #pragma unroll
  for (int i=0;i<4;i++)
    #pragma unroll
    for (int j=0;j<4;j++) acc[i][j] = (f32x4){0.f,0.f,0.f,0.f};

  const int c1 = tid, c2 = tid + 256;
  const int r1 = c1>>2, s1 = c1&3, k1 = ((s1 ^ ((r1>>1)&3))&3)<<3;
  const int r2 = c2>>2, s2 = c2&3, k2 = ((s2 ^ ((r2>>1)&3))&3)<<3;
  const short* sAs = (const short*)sA;
  const short* sBs = (const short*)sB;
  const int fr = lane & 15;                       // frag row (A) / col (B)
  const int fq = lane >> 4;                       // k-slot 0..3
  const int fk = ((fq ^ ((fr>>1)&3))&3)<<3;       // swizzled k offset (shorts)

  for (int ks = 0; ks < K; ks += 32) {
    gload_lds16(A  + (size_t)(m0 + r1)*lda + ks + k1, &sA[c1]);
    gload_lds16(A  + (size_t)(m0 + r2)*lda + ks + k2, &sA[c2]);
    gload_lds16(Bt + (size_t)(n0 + r1)*ldb + ks + k1, &sB[c1]);
    gload_lds16(Bt + (size_t)(n0 + r2)*ldb + ks + k2, &sB[c2]);
    __syncthreads();
    bf16x8 af[4], bfr[4];
    #pragma unroll
    for (int i=0;i<4;i++){
      af[i]  = *(const bf16x8*)(sAs + (wr + i*16 + fr)*32 + fk);
      bfr[i] = *(const bf16x8*)(sBs + (wc + i*16 + fr)*32 + fk);
    }
    #pragma unroll
    for (int i=0;i<4;i++)
      #pragma unroll
      for (int j=0;j<4;j++)
        acc[i][j] = __builtin_amdgcn_mfma_f32_16x16x32_bf16(af[i], bfr[j], acc[i][j], 0,0,0);
    __syncthreads();
  }

  const int orow = fq<<2;   // C/D: col=lane&15, row=(lane>>4)*4+reg
  #pragma unroll
  for (int i=0;i<4;i++){
    #pragma unroll
    for (int j=0;j<4;j++){
      const int gn = n0 + wc + j*16 + fr;
      const float bv = bias ? bias[gn] : 0.f;
      #pragma unroll
      for (int v=0;v<4;v++){
        const int gm = m0 + wr + i*16 + orow + v;
        C[(size_t)gm*ldc + gn] = f2bf(acc[i][j][v] + bv);
      }
    }
  }
}

// ---------------------------------------------------------------------------
// Fused gates GEMM + GRU. gates[128 rows x 512 cols] = X2tile @ wG^T, then
// GRU elementwise -> hidden (bf16). 8 waves (2 row x 4 col groups), BK=32.
// Epilogue: exchange f32 acc through LDS (reusing sB) in 8 chunks of 16 rows.
// ---------------------------------------------------------------------------
__global__ __launch_bounds__(512)
void k_gates_gru(const unsigned short* __restrict__ X2,
                 const unsigned short* __restrict__ wG,
                 const float* __restrict__ biasG,
                 unsigned short* __restrict__ hidden)
{
  __shared__ __align__(16) short sA[128*32];      // 8KB
  __shared__ __align__(16) char  sBx[512*32*2];   // 32KB: sB (short) / xch (float)
  short* sB  = (short*)sBx;
  float* xch = (float*)sBx;

  const int tid = threadIdx.x;
  const int m0 = blockIdx.x * 128;
  const int lane = tid & 63;
  const int w = tid >> 6;
  const int wr = (w>>2)*64;          // 0 | 64
  const int wc = (w&3)*128;          // 0 | 128 | 256 | 384
  const int fr = lane & 15;
  const int fq = lane >> 4;
  const int fk = ((fq ^ ((fr>>1)&3))&3)<<3;

  f32x4 acc[4][8];
  #pragma unroll
  for (int i=0;i<4;i++)
    #pragma unroll
    for (int j=0;j<8;j++) acc[i][j] = (f32x4){0.f,0.f,0.f,0.f};

  // A staging: 256 chunks (threads 0..255). B staging: 2048 chunks, 4/thread.
  const int ra = tid>>2, sa = tid&3, ka = ((sa ^ ((ra>>1)&3))&3)<<3;

  for (int ks = 0; ks < 384; ks += 32) {
    if (tid < 256)
      gload_lds16(X2 + (size_t)(m0 + ra)*384 + ks + ka, sA + tid*8);
    #pragma unroll
    for (int q=0;q<4;q++){
      const int c = tid + q*512;
      const int rb = c>>2, sb = c&3, kb = ((sb ^ ((rb>>1)&3))&3)<<3;
      gload_lds16(wG + (size_t)rb*384 + ks + kb, sB + c*8);
    }
    __syncthreads();
    bf16x8 af[4], bfr[8];
    #pragma unroll
    for (int i=0;i<4;i++)
      af[i]  = *(const bf16x8*)(sA + (wr + i*16 + fr)*32 + fk);
    #pragma unroll
    for (int j=0;j<8;j++)
      bfr[j] = *(const bf16x8*)(sB + (wc + j*16 + fr)*32 + fk);
    #pragma unroll
    for (int i=0;i<4;i++)
      #pragma unroll
      for (int j=0;j<8;j++)
        acc[i][j] = __builtin_amdgcn_mfma_f32_16x16x32_bf16(af[i], bfr[j], acc[i][j], 0,0,0);
    __syncthreads();
  }

  // Epilogue: 8 chunks of 16 rows.
  const int d  = tid & 127;
  const int r4 = (tid>>7)<<2;
  const float bg0 = biasG[d], bg1 = biasG[128+d], bg2 = biasG[256+d], bg3 = biasG[384+d];
  #pragma unroll
  for (int c=0;c<8;c++){
    if ((w>>2) == (c>>2)) {            // 4 waves own this 16-row stripe
      const int i = c&3;
      #pragma unroll
      for (int j=0;j<8;j++){
        #pragma unroll
        for (int v=0;v<4;v++){
          const int rl = fq*4 + v;
          xch[rl*512 + wc + j*16 + fr] = acc[i][j][v];
        }
      }
    }
    __syncthreads();
    #pragma unroll
    for (int p=0;p<4;p++){
      const int rl = r4 + p;
      const int row = m0 + c*16 + rl;
      const float g0 = xch[rl*512 +       d] + bg0;
      const float g1 = xch[rl*512 + 128 + d] + bg1;
      const float g2 = xch[rl*512 + 256 + d] + bg2;
      const float g3 = xch[rl*512 + 384 + d] + bg3;
      const float h  = bf2f(X2[(size_t)row*384 + 256 + d]);
      const float r = 1.f/(1.f+__expf(-g0));
      const float z = 1.f/(1.f+__expf(-g1));
      const float x = g2 + r*g3;
      const float n = 1.f - 2.f/(__expf(2.f*x)+1.f);   // tanh
      hidden[(size_t)row*128 + d] = f2bf((1.f-z)*h + z*n);
    }
    __syncthreads();
  }
}

// ---------------------------------------------------------------------------
// Weight prep: fp32 -> bf16 packed matrices + fused biases
// ---------------------------------------------------------------------------
__global__ __launch_bounds__(256)
void k_prep(const float* __restrict__ W_in, const float* __restrict__ b_in,
            const float* __restrict__ W_out, const float* __restrict__ b_out,
            const float* __restrict__ w_ih, const float* __restrict__ w_hh,
            const float* __restrict__ b_ih, const float* __restrict__ b_hh,
            const float* __restrict__ W1, const float* __restrict__ W2,
            unsigned short* __restrict__ wE, unsigned short* __restrict__ wG,
            unsigned short* __restrict__ w1b, unsigned short* __restrict__ w2b,
            float* __restrict__ biasE, float* __restrict__ biasG)
{
  const int i = blockIdx.x*256 + threadIdx.x;
  if (i < 32768) {                       // wE [256][128] = [W_in; W_out]
    int n = i>>7, k = i&127;
    float v = (n<128) ? W_in[n*128+k] : W_out[(n-128)*128+k];
    wE[i] = f2bf(v);
  }
  if (i < 196608) {                      // wG [512][384]
    int n = i/384, k = i - n*384;
    float v;
    if (n < 256)      v = (k<256) ? w_ih[n*256+k] : w_hh[n*128 + (k-256)];
    else if (n < 384) v = (k<256) ? w_ih[n*256+k] : 0.f;       // i_n
    else              v = (k<256) ? 0.f : w_hh[(n-128)*128 + (k-256)]; // h_n
    wG[i] = f2bf(v);
  }
  if (i < 16384) { w1b[i] = f2bf(W1[i]); w2b[i] = f2bf(W2[i]); }
  if (i < 256) biasE[i] = (i<128) ? b_in[i] : b_out[i-128];
  if (i < 512) {
    float v;
    if (i < 256)      v = b_ih[i] + b_hh[i];
    else if (i < 384) v = b_ih[i];
    else              v = b_hh[i-128];
    biasG[i] = v;
  }
}

// ---------------------------------------------------------------------------
// Embedding gather: X2[:,256:384] = bf16(item_emb[items])
// ---------------------------------------------------------------------------
__global__ __launch_bounds__(256)
void k_embed(const int* __restrict__ items, const float* __restrict__ emb,
             unsigned short* __restrict__ X2)
{
  const int idx = blockIdx.x*256 + threadIdx.x;  // M*32 threads, 4 dims each
  const int row = idx >> 5, d4 = (idx & 31) << 2;
  const int it = items[row];
  const float4 v = *(const float4*)(emb + (size_t)it*128 + d4);
  ushort4 o; o.x=f2bf(v.x); o.y=f2bf(v.y); o.z=f2bf(v.z); o.w=f2bf(v.w);
  *(ushort4*)(X2 + (size_t)row*384 + 256 + d4) = o;
}

// ---------------------------------------------------------------------------
// Graph aggregation, one 1024-thread block per batch. Dedup bitmaps via
// LDS atomicOr (idempotent -> deterministic). 8 row-groups x 128 dims.
// X2[:,0:128] = input_in + b_iah ; X2[:,128:256] = input_out + b_ioh
// ---------------------------------------------------------------------------
__global__ __launch_bounds__(1024)
void k_agg(const int* __restrict__ alias, const int* __restrict__ lens,
           const unsigned short* __restrict__ E, unsigned short* __restrict__ X2,
           const float* __restrict__ b_iah, const float* __restrict__ b_ioh)
{
  const int b = blockIdx.x, tid = threadIdx.x;
  __shared__ int al[L_];
  __shared__ unsigned bmIn[L_*8], bmOut[L_*8];
  if (tid < L_) al[tid] = alias[b*L_ + tid];
  for (int i=tid; i<L_*8; i+=1024){ bmIn[i]=0u; bmOut[i]=0u; }
  __syncthreads();
  const int len = lens[b];
  if (tid < len-1) {
    const int r = al[tid], c = al[tid+1];
    atomicOr(&bmIn[c*8 + (r>>5)],  1u<<(r&31));
    atomicOr(&bmOut[r*8 + (c>>5)], 1u<<(c&31));
  }
  __syncthreads();
  const int g = tid >> 7, d = tid & 127;   // 8 row-groups x 128 dims
  const float bi = b_iah[d], bo = b_ioh[d];
  for (int base=0; base<L_; base+=8) {
    const int i = base + g;
    float si=0.f, so=0.f; int ci=0, co=0;
    #pragma unroll
    for (int wd=0; wd<8; ++wd) {
      unsigned word = bmIn[i*8+wd];
      while (word) { int j = __ffs(word)-1; word &= word-1u;
        si += bf2f(E[((size_t)(b*L_ + wd*32 + j))*256 + d]); ci++; }
      word = bmOut[i*8+wd];
      while (word) { int j = __ffs(word)-1; word &= word-1u;
        so += bf2f(E[((size_t)(b*L_ + wd*32 + j))*256 + 128 + d]); co++; }
    }
    const float vin  = si / (float)(ci>0?ci:1) + bi;
    const float vout = so / (float)(co>0?co:1) + bo;
    unsigned short* xr = X2 + (size_t)(b*L_ + i)*384;
    xr[d] = f2bf(vin); xr[128+d] = f2bf(vout);
  }
}

// ---------------------------------------------------------------------------
// seq_hidden gather + ht extraction
// ---------------------------------------------------------------------------
__global__ __launch_bounds__(256)
void k_gather(const unsigned short* __restrict__ hidden,
              const int* __restrict__ alias, const int* __restrict__ lens,
              unsigned short* __restrict__ seqh, unsigned short* __restrict__ htb)
{
  const int idx = blockIdx.x*256 + threadIdx.x;  // M*16
  const int row = idx >> 4, d8 = (idx & 15) << 3;
  const int b = row / L_, l = row - b*L_;
  const int alv = alias[row];
  u16x8 v = *(const u16x8*)(hidden + (size_t)(b*L_ + alv)*128 + d8);
  *(u16x8*)(seqh + (size_t)row*128 + d8) = v;
  if (l == lens[b]-1) *(u16x8*)(htb + (size_t)b*128 + d8) = v;
}

// ---------------------------------------------------------------------------
// LN + LIF(4 steps, constant input) + alpha = Qs.W3 + masked sum -> a[T,B,D]
// One 1024-thread block per batch; one wave per row (lane: dims d, d+64).
// ---------------------------------------------------------------------------
__global__ __launch_bounds__(1024)
void k_attn(const unsigned short* __restrict__ Q0, const unsigned short* __restrict__ htW1,
            const unsigned short* __restrict__ seqh, const int* __restrict__ lens,
            const float* __restrict__ g_q, const float* __restrict__ beta_q,
            const float* __restrict__ W3, float* __restrict__ a_out)
{
  const int b = blockIdx.x, tid = threadIdx.x;
  const int w = tid>>6, lane = tid&63;
  __shared__ float a_acc[16][T_][128];
  for (int i=tid; i<16*T_*128; i+=1024) ((float*)a_acc)[i] = 0.f;
  const float h0 = bf2f(htW1[b*128 + lane]), h1 = bf2f(htW1[b*128 + lane + 64]);
  const float gq0 = g_q[lane], gq1 = g_q[lane+64];
  const float bq0 = beta_q[lane], bq1 = beta_q[lane+64];
  const float w30 = W3[lane], w31 = W3[lane+64];
  const int len = lens[b];
  __syncthreads();
  for (int l = w; l < L_; l += 16) {
    const size_t row = (size_t)b*L_ + l;
    const float q0 = bf2f(Q0[row*128 + lane]) + h0;
    const float q1 = bf2f(Q0[row*128 + lane + 64]) + h1;
    const float m = wsum(q0+q1) * (1.f/128.f);
    const float d0 = q0-m, d1 = q1-m;
    const float var = wsum(d0*d0 + d1*d1) * (1.f/128.f);
    const float inv = rsqrtf(var + 1e-5f);
    const float x0 = d0*inv*gq0 + bq0;
    const float x1 = d1*inv*gq1 + bq1;
    const float sh0 = bf2f(seqh[row*128+lane]), sh1 = bf2f(seqh[row*128+lane+64]);
    const bool active = (l < len);
    float v0=0.f, v1=0.f;
    #pragma unroll
    for (int t=0;t<T_;t++){
      v0 = 0.5f*(v0+x0); v1 = 0.5f*(v1+x1);
      const float s0 = (v0>=1.f)?1.f:0.f, s1 = (v1>=1.f)?1.f:0.f;
      v0 -= s0*v0; v1 -= s1*v1;
      const float alpha = wsum(s0*w30 + s1*w31);
      if (active){ a_acc[w][t][lane] += alpha*sh0; a_acc[w][t][lane+64] += alpha*sh1; }
    }
  }
  __syncthreads();
  for (int i=tid; i<T_*128; i+=1024){
    const int t = i>>7, d = i&127;
    float s = 0.f;
    #pragma unroll
    for (int p=0;p<16;p++) s += a_acc[p][t][d];
    a_out[((size_t)t*B_ + b)*128 + d] = s;
  }
}

// ---------------------------------------------------------------------------
// Final: sh=[a,ht], LIF over T (sequential), LN(binary spikes), @Wt.T, mean_T
// One block per batch, 256 threads (= 2D dims).
// ---------------------------------------------------------------------------
__global__ __launch_bounds__(256)
void k_final(const float* __restrict__ a_in, const unsigned short* __restrict__ hidden,
             const int* __restrict__ alias, const int* __restrict__ lens,
             const float* __restrict__ g_sh, const float* __restrict__ beta_sh,
             const float* __restrict__ Wt, float* __restrict__ out)
{
  const int b = blockIdx.x, tid = threadIdx.x;
  const int w = tid>>6, lane = tid&63;
  __shared__ float yl[T_][256];
  __shared__ float part[T_][4];
  const int len = lens[b];
  float xh = 0.f;
  if (tid >= 128) {
    const int al = alias[b*L_ + len - 1];
    xh = bf2f(hidden[((size_t)(b*L_ + al))*128 + (tid-128)]);
  }
  float v = 0.f; float sp[T_];
  #pragma unroll
  for (int t=0;t<T_;t++){
    const float x = (tid<128) ? a_in[((size_t)t*B_ + b)*128 + tid] : xh;
    v = 0.5f*(v + x);
    const float s = (v>=1.f)?1.f:0.f;
    v -= s*v;
    sp[t] = s;
  }
  #pragma unroll
  for (int t=0;t<T_;t++){
    const float r = wsum(sp[t]);
    if (lane==0) part[t][w] = r;
  }
  __syncthreads();
  #pragma unroll
  for (int t=0;t<T_;t++){
    const float k = part[t][0]+part[t][1]+part[t][2]+part[t][3];
    const float mean = k * (1.f/256.f);
    const float varr = mean - mean*mean;   // spikes are binary: E[x^2]=E[x]
    const float inv = rsqrtf(varr + 1e-5f);
    yl[t][tid] = (sp[t]-mean)*inv*g_sh[tid] + beta_sh[tid];
  }
  __syncthreads();
  if (tid < 128) {
    float acc = 0.f;
    const float* wr = Wt + (size_t)tid*256;
    for (int k=0;k<256;k++)
      acc += wr[k]*(yl[0][k]+yl[1][k]+yl[2][k]+yl[3][k]);
    out[(size_t)b*128 + tid] = acc*0.25f;
  }
}

// ---------------------------------------------------------------------------
extern "C" void kernel_launch(void* const* d_in, const int* in_sizes, int n_in,
                              void* d_out, int out_size, void* d_ws, size_t ws_size,
                              hipStream_t stream)
{
  const int*   alias  = (const int*)d_in[1];
  const int*   items  = (const int*)d_in[2];
  const int*   lens   = (const int*)d_in[4];
  const float* emb    = (const float*)d_in[5];
  const float* W_in   = (const float*)d_in[6];
  const float* b_in   = (const float*)d_in[7];
  const float* W_out  = (const float*)d_in[8];
  const float* b_out  = (const float*)d_in[9];
  const float* w_ih   = (const float*)d_in[10];
  const float* w_hh   = (const float*)d_in[11];
  const float* b_ih   = (const float*)d_in[12];
  const float* b_hh   = (const float*)d_in[13];
  const float* b_iah  = (const float*)d_in[14];
  const float* b_ioh  = (const float*)d_in[15];
  const float* W1     = (const float*)d_in[16];
  const float* W2     = (const float*)d_in[17];
  const float* W3     = (const float*)d_in[18];
  const float* Wt     = (const float*)d_in[19];
  const float* g_q    = (const float*)d_in[20];
  const float* beta_q = (const float*)d_in[21];
  const float* g_sh   = (const float*)d_in[22];
  const float* beta_sh= (const float*)d_in[23];

  char* ws = (char*)d_ws;
  size_t off = 0;
  auto alloc = [&](size_t bytes)->void* {
    void* p = ws + off; off += (bytes + 255) & ~(size_t)255; return p;
  };
  unsigned short* X2    = (unsigned short*)alloc((size_t)M_*384*2);   // [in|out|hidden]
  unsigned short* Eg    = (unsigned short*)alloc((size_t)M_*512*2);   // E -> Q0 (reused)
  unsigned short* hidden= (unsigned short*)alloc((size_t)M_*128*2);
  unsigned short* seqh  = (unsigned short*)alloc((size_t)M_*128*2);
  unsigned short* htb   = (unsigned short*)alloc((size_t)B_*128*2);
  unsigned short* htW1  = (unsigned short*)alloc((size_t)B_*128*2);
  float*          a_buf = (float*)alloc((size_t)T_*B_*128*4);
  unsigned short* wE    = (unsigned short*)alloc(32768*2);
  unsigned short* wG    = (unsigned short*)alloc((size_t)196608*2);
  unsigned short* w1b   = (unsigned short*)alloc(16384*2);
  unsigned short* w2b   = (unsigned short*)alloc(16384*2);
  float*          biasE = (float*)alloc(256*4);
  float*          biasG = (float*)alloc(512*4);
  if (off > ws_size) return;  // workspace too small -> visible as validation failure

  unsigned short* E     = Eg;            // [M,256]
  unsigned short* Q0    = Eg;            // [M,128] (E dead)

  k_prep<<<768,256,0,stream>>>(W_in,b_in,W_out,b_out,w_ih,w_hh,b_ih,b_hh,W1,W2,
                               wE,wG,w1b,w2b,biasE,biasG);
  k_embed<<<M_*32/256,256,0,stream>>>(items, emb, X2);
  gemm_bt<<<dim3(2,800),256,0,stream>>>(X2+256, 384, wE, 128, biasE, E, 256, 128);
  k_agg<<<B_,1024,0,stream>>>(alias, lens, E, X2, b_iah, b_ioh);
  k_gates_gru<<<800,512,0,stream>>>(X2, wG, biasG, hidden);
  k_gather<<<M_*16/256,256,0,stream>>>(hidden, alias, lens, seqh, htb);
  gemm_bt<<<dim3(1,4),256,0,stream>>>(htb, 128, w1b, 128, nullptr, htW1, 128, 128);
  gemm_bt<<<dim3(1,800),256,0,stream>>>(seqh, 128, w2b, 128, nullptr, Q0, 128, 128);
  k_attn<<<B_,1024,0,stream>>>(Q0, htW1, seqh, lens, g_q, beta_q, W3, a_buf);
  k_final<<<B_,256,0,stream>>>(a_buf, hidden, alias, lens, g_sh, beta_sh, Wt, (float*)d_out);
}

// Round 4
// 228.568 us; speedup vs baseline: 1.9421x; 1.2323x over previous
//
#include <hip/hip_runtime.h>
#include <hip/hip_bf16.h>
#include <cstdint>
#include <cstddef>

#define B_ 512
#define L_ 200
#define D_ 128
#define M_ (B_*L_)
#define T_ 4

typedef short bf16x8 __attribute__((ext_vector_type(8)));
typedef unsigned short u16x8 __attribute__((ext_vector_type(8)));
typedef float f32x4 __attribute__((ext_vector_type(4)));

__device__ __forceinline__ float bf2f(unsigned short u){
  union { unsigned int i; float f; } c; c.i = ((unsigned int)u)<<16; return c.f;
}
__device__ __forceinline__ unsigned short f2bf(float f){
  union { float f; unsigned int i; } c; c.f = f;
  unsigned int r = c.i + 0x7FFFu + ((c.i>>16)&1u);
  return (unsigned short)(r>>16);
}
__device__ __forceinline__ float wsum(float v){
  #pragma unroll
  for (int m=1;m<64;m<<=1) v += __shfl_xor(v, m, 64);
  return v;
}
__device__ __forceinline__ void gload_lds16(const void* g, void* l){
  __builtin_amdgcn_global_load_lds(
      (const __attribute__((address_space(1))) void*)g,
      (__attribute__((address_space(3))) void*)l, 16, 0, 0);
}

// ---------------------------------------------------------------------------
// Generic bf16 GEMM, C[M,N] = A[M,K] @ Bt[N,K]^T + bias, bf16 out.
// 128x128 tile, BK=32, 4 waves, 16x16x32 MFMA, slot-swizzled LDS.
// ---------------------------------------------------------------------------
__global__ __launch_bounds__(256)
void gemm_bt(const unsigned short* __restrict__ A, int lda,
             const unsigned short* __restrict__ Bt, int ldb,
             const float* __restrict__ bias,
             unsigned short* __restrict__ C, int ldc, int K)
{
  __shared__ __align__(16) short sAs[128*32];
  __shared__ __align__(16) short sBs[128*32];
  const int tid = threadIdx.x;
  const int m0 = blockIdx.y * 128;
  const int n0 = blockIdx.x * 128;
  const int lane = tid & 63;
  const int w = tid >> 6;
  const int wr = (w>>1)*64, wc = (w&1)*64;

  f32x4 acc[4][4];
  #pragma unroll
  for (int i=0;i<4;i++)
    #pragma unroll
    for (int j=0;j<4;j++) acc[i][j] = (f32x4){0.f,0.f,0.f,0.f};

  const int c1 = tid, c2 = tid + 256;
  const int r1 = c1>>2, s1 = c1&3, k1 = ((s1 ^ ((r1>>1)&3))&3)<<3;
  const int r2 = c2>>2, s2 = c2&3, k2 = ((s2 ^ ((r2>>1)&3))&3)<<3;
  const int fr = lane & 15;
  const int fq = lane >> 4;
  const int fk = ((fq ^ ((fr>>1)&3))&3)<<3;

  for (int ks = 0; ks < K; ks += 32) {
    gload_lds16(A  + (size_t)(m0 + r1)*lda + ks + k1, sAs + (size_t)c1*8);
    gload_lds16(A  + (size_t)(m0 + r2)*lda + ks + k2, sAs + (size_t)c2*8);
    gload_lds16(Bt + (size_t)(n0 + r1)*ldb + ks + k1, sBs + (size_t)c1*8);
    gload_lds16(Bt + (size_t)(n0 + r2)*ldb + ks + k2, sBs + (size_t)c2*8);
    __syncthreads();
    bf16x8 af[4], bfr[4];
    #pragma unroll
    for (int i=0;i<4;i++){
      af[i]  = *(const bf16x8*)(sAs + (wr + i*16 + fr)*32 + fk);
      bfr[i] = *(const bf16x8*)(sBs + (wc + i*16 + fr)*32 + fk);
    }
    #pragma unroll
    for (int i=0;i<4;i++)
      #pragma unroll
      for (int j=0;j<4;j++)
        acc[i][j] = __builtin_amdgcn_mfma_f32_16x16x32_bf16(af[i], bfr[j], acc[i][j], 0,0,0);
    __syncthreads();
  }

  const int orow = fq<<2;
  #pragma unroll
  for (int i=0;i<4;i++){
    #pragma unroll
    for (int j=0;j<4;j++){
      const int gn = n0 + wc + j*16 + fr;
      const float bv = bias ? bias[gn] : 0.f;
      #pragma unroll
      for (int v=0;v<4;v++){
        const int gm = m0 + wr + i*16 + orow + v;
        C[(size_t)gm*ldc + gn] = f2bf(acc[i][j][v] + bv);
      }
    }
  }
}

// ---------------------------------------------------------------------------
// Weight prep: combined Wbig[512][384] (gate-interleaved rows p = dim*4+g):
//   cols 0:128   = (w_ih_left  @ W_in )[row_g]   (g in {0,1,2})
//   cols 128:256 = (w_ih_right @ W_out)[row_g]   (g in {0,1,2})
//   cols 256:384 = w_hh[row_g]                   (g in {0,1,3})
// plus biasBase/uIn/uOut[512] (permuted index).
// One block per p-row, 128 threads.
// ---------------------------------------------------------------------------
__global__ __launch_bounds__(128)
void k_prepW(const float* __restrict__ w_ih, const float* __restrict__ w_hh,
             const float* __restrict__ W_in, const float* __restrict__ W_out,
             const float* __restrict__ b_in, const float* __restrict__ b_out,
             const float* __restrict__ b_ih, const float* __restrict__ b_hh,
             const float* __restrict__ b_iah, const float* __restrict__ b_ioh,
             unsigned short* __restrict__ Wbig, float* __restrict__ biasBase,
             float* __restrict__ uIn, float* __restrict__ uOut)
{
  const int p = blockIdx.x, t = threadIdx.x;
  const int dim = p>>2, g = p&3;
  const int row = (g==0) ? dim : (g==1) ? 128+dim : 256+dim;
  const bool has_ih = (g!=3), has_hh = (g!=2);
  __shared__ float wl[128], wrg[128], red[3][128];
  wl[t]  = has_ih ? w_ih[(size_t)row*256 + t]       : 0.f;
  wrg[t] = has_ih ? w_ih[(size_t)row*256 + 128 + t] : 0.f;
  __syncthreads();
  float cin = 0.f, cout = 0.f;
  if (has_ih) {
    for (int m=0;m<128;m++){
      cin  += wl[m]  * W_in [m*128 + t];
      cout += wrg[m] * W_out[m*128 + t];
    }
  }
  Wbig[(size_t)p*384 +       t] = f2bf(cin);
  Wbig[(size_t)p*384 + 128 + t] = f2bf(cout);
  Wbig[(size_t)p*384 + 256 + t] = f2bf(has_hh ? w_hh[(size_t)row*128 + t] : 0.f);
  red[0][t] = wl[t]*b_iah[t] + wrg[t]*b_ioh[t];
  red[1][t] = wl[t]*b_in[t];
  red[2][t] = wrg[t]*b_out[t];
  __syncthreads();
  if (t == 0) {
    float v=0.f, ui=0.f, uo=0.f;
    for (int k=0;k<128;k++){ v += red[0][k]; ui += red[1][k]; uo += red[2][k]; }
    float bb;
    if (g==0)      bb = b_ih[dim]     + b_hh[dim]     + v;
    else if (g==1) bb = b_ih[128+dim] + b_hh[128+dim] + v;
    else if (g==2) bb = b_ih[256+dim] + v;
    else           bb = b_hh[256+dim];
    biasBase[p] = bb;
    uIn[p]  = has_ih ? ui : 0.f;
    uOut[p] = has_ih ? uo : 0.f;
  }
}

// ---------------------------------------------------------------------------
// Small weights: W1/W2 -> bf16
// ---------------------------------------------------------------------------
__global__ __launch_bounds__(256)
void k_prepSmall(const float* __restrict__ W1, const float* __restrict__ W2,
                 unsigned short* __restrict__ w1b, unsigned short* __restrict__ w2b)
{
  const int i = blockIdx.x*256 + threadIdx.x;
  if (i < 16384) { w1b[i] = f2bf(W1[i]); w2b[i] = f2bf(W2[i]); }
}

// ---------------------------------------------------------------------------
// Fused embedding gather + graph aggregation, one 1024-thread block per batch.
// Stages the batch's 200 embedding rows in LDS (bf16, 50KB), writes the h
// section of X3, builds dedup edge bitmaps (atomicOr, idempotent ->
// deterministic), then aggregates from LDS.
// X3[:,0:128]=aggIn, X3[:,128:256]=aggOut, X3[:,256:384]=h. cf = degree flags.
// ---------------------------------------------------------------------------
__global__ __launch_bounds__(1024)
void k_aggemb(const int* __restrict__ alias, const int* __restrict__ items,
              const int* __restrict__ lens, const float* __restrict__ emb,
              unsigned short* __restrict__ X3, unsigned char* __restrict__ cf)
{
  const int b = blockIdx.x, tid = threadIdx.x;
  __shared__ unsigned short hl[L_*128];        // 50KB
  __shared__ int al[L_], it[L_];
  __shared__ unsigned bmIn[L_*8], bmOut[L_*8]; // 12.8KB
  if (tid < L_) { al[tid] = alias[b*L_ + tid]; it[tid] = items[b*L_ + tid]; }
  for (int i=tid; i<L_*8; i+=1024){ bmIn[i]=0u; bmOut[i]=0u; }
  __syncthreads();
  const int len = lens[b];
  if (tid < len-1) {
    const int r = al[tid], c = al[tid+1];
    atomicOr(&bmIn[c*8 + (r>>5)],  1u<<(r&31));
    atomicOr(&bmOut[r*8 + (c>>5)], 1u<<(c&31));
  }
  // embedding stage: 32 rows in parallel, 32 threads x float4 per row
  const int rr = tid>>5, cc = (tid&31)<<2;
  for (int base=0; base<L_; base+=32) {
    const int l = base + rr;
    if (l < L_) {
      const float4 v = *(const float4*)(emb + (size_t)it[l]*128 + cc);
      ushort4 o; o.x=f2bf(v.x); o.y=f2bf(v.y); o.z=f2bf(v.z); o.w=f2bf(v.w);
      *(ushort4*)(hl + l*128 + cc) = o;
      *(ushort4*)(X3 + (size_t)(b*L_ + l)*384 + 256 + cc) = o;
    }
  }
  __syncthreads();
  const int g = tid >> 7, d = tid & 127;   // 8 row-groups x 128 dims
  for (int base=0; base<L_; base+=8) {
    const int i = base + g;
    float si=0.f, so=0.f; int ci=0, co=0;
    #pragma unroll
    for (int wd=0; wd<8; ++wd) {
      unsigned word = bmIn[i*8+wd];
      while (word) { int j = __ffs(word)-1; word &= word-1u;
        si += bf2f(hl[(wd*32+j)*128 + d]); ci++; }
      word = bmOut[i*8+wd];
      while (word) { int j = __ffs(word)-1; word &= word-1u;
        so += bf2f(hl[(wd*32+j)*128 + d]); co++; }
    }
    unsigned short* xr = X3 + (size_t)(b*L_ + i)*384;
    xr[d]       = f2bf(si / (float)(ci>0?ci:1));
    xr[128 + d] = f2bf(so / (float)(co>0?co:1));
    if (d == 0) cf[b*L_ + i] = (unsigned char)((ci>0?1:0) | (co>0?2:0));
  }
}

// ---------------------------------------------------------------------------
// Fused gates GEMM + GRU, register-only epilogue.
// C[128 rows x 256 pcols] = X3 @ Wbig^T (pcol = dim*4+gate), 8 waves (2x4),
// BK=32. Quad 4x4 shuffle-transpose puts the 4 gates of one (row,dim) in one
// lane; GRU applied in registers; writes hidden bf16. No epilogue LDS.
// ---------------------------------------------------------------------------
__global__ __launch_bounds__(512)
void k_gates_gru(const unsigned short* __restrict__ X3,
                 const unsigned short* __restrict__ Wbig,
                 const float* __restrict__ biasBase,
                 const float* __restrict__ uIn,
                 const float* __restrict__ uOut,
                 const unsigned char* __restrict__ cf,
                 unsigned short* __restrict__ hidden)
{
  __shared__ __align__(16) short sA[128*32];   // 8KB
  __shared__ __align__(16) short sB[256*32];   // 16KB
  const int tid = threadIdx.x;
  const int m0 = blockIdx.y * 128;
  const int p0 = blockIdx.x * 256;
  const int lane = tid & 63;
  const int w = tid >> 6;
  const int wr  = (w>>2)*64;          // row group: 0 | 64
  const int wcp = (w&3)*64;           // pcol group: 0..192
  const int fr = lane & 15;
  const int fq = lane >> 4;
  const int fk = ((fq ^ ((fr>>1)&3))&3)<<3;

  f32x4 acc[4][4];
  #pragma unroll
  for (int i=0;i<4;i++)
    #pragma unroll
    for (int j=0;j<4;j++) acc[i][j] = (f32x4){0.f,0.f,0.f,0.f};

  const int ra = tid>>2, sa_ = tid&3, ka = ((sa_ ^ ((ra>>1)&3))&3)<<3;
  const int c1 = tid + 512, rb1 = c1>>2, sb1 = c1&3, kb1 = ((sb1 ^ ((rb1>>1)&3))&3)<<3;

  for (int ks = 0; ks < 384; ks += 32) {
    gload_lds16(X3   + (size_t)(m0 + ra )*384 + ks + ka , sA + (size_t)tid*8);
    gload_lds16(Wbig + (size_t)(p0 + ra )*384 + ks + ka , sB + (size_t)tid*8);
    gload_lds16(Wbig + (size_t)(p0 + rb1)*384 + ks + kb1, sB + (size_t)c1*8);
    __syncthreads();
    bf16x8 af[4], bfr[4];
    #pragma unroll
    for (int i=0;i<4;i++){
      af[i]  = *(const bf16x8*)(sA + (wr  + i*16 + fr)*32 + fk);
      bfr[i] = *(const bf16x8*)(sB + (wcp + i*16 + fr)*32 + fk);
    }
    #pragma unroll
    for (int i=0;i<4;i++)
      #pragma unroll
      for (int j=0;j<4;j++)
        acc[i][j] = __builtin_amdgcn_mfma_f32_16x16x32_bf16(af[i], bfr[j], acc[i][j], 0,0,0);
    __syncthreads();
  }

  // Epilogue: per frag, 4x4 quad transpose (v <-> lane&3), then GRU.
  const bool q0b = (lane & 1), q1b = (lane & 2);
  #pragma unroll
  for (int j=0;j<4;j++){
    const int dim = (p0>>2) + (w&3)*16 + j*4 + ((lane>>2)&3);
    const float4 bb = *(const float4*)(biasBase + dim*4);
    const float4 bi = *(const float4*)(uIn  + dim*4);
    const float4 bo = *(const float4*)(uOut + dim*4);
    #pragma unroll
    for (int i=0;i<4;i++){
      const float a0=acc[i][j][0], a1=acc[i][j][1], a2=acc[i][j][2], a3=acc[i][j][3];
      const float t0=__shfl_xor(a0,1), t1=__shfl_xor(a1,1), t2=__shfl_xor(a2,1), t3=__shfl_xor(a3,1);
      const float s0 = q0b? t1:a0, s1 = q0b? a1:t0, s2 = q0b? t3:a2, s3 = q0b? a3:t2;
      const float u0=__shfl_xor(s0,2), u1=__shfl_xor(s1,2), u2=__shfl_xor(s2,2), u3=__shfl_xor(s3,2);
      float G0 = q1b? u2:s0, G1 = q1b? u3:s1, G2 = q1b? s2:u0, G3 = q1b? s3:u1;
      const int row = m0 + wr + i*16 + fq*4 + (lane&3);
      const unsigned c = cf[row];
      const float fi = (c&1) ? 1.f : 0.f, fo = (c&2) ? 1.f : 0.f;
      G0 += bb.x + fi*bi.x + fo*bo.x;
      G1 += bb.y + fi*bi.y + fo*bo.y;
      G2 += bb.z + fi*bi.z + fo*bo.z;
      G3 += bb.w;                          // uIn/uOut are 0 for g3
      const float h = bf2f(X3[(size_t)row*384 + 256 + dim]);
      const float r = 1.f/(1.f+__expf(-G0));
      const float z = 1.f/(1.f+__expf(-G1));
      const float x = G2 + r*G3;
      const float n = 1.f - 2.f/(__expf(2.f*x)+1.f);   // tanh
      hidden[(size_t)row*128 + dim] = f2bf((1.f-z)*h + z*n);
    }
  }
}

// ---------------------------------------------------------------------------
// seq_hidden gather + ht extraction
// ---------------------------------------------------------------------------
__global__ __launch_bounds__(256)
void k_gather(const unsigned short* __restrict__ hidden,
              const int* __restrict__ alias, const int* __restrict__ lens,
              unsigned short* __restrict__ seqh, unsigned short* __restrict__ htb)
{
  const int idx = blockIdx.x*256 + threadIdx.x;  // M*16
  const int row = idx >> 4, d8 = (idx & 15) << 3;
  const int b = row / L_, l = row - b*L_;
  const int alv = alias[row];
  u16x8 v = *(const u16x8*)(hidden + (size_t)(b*L_ + alv)*128 + d8);
  *(u16x8*)(seqh + (size_t)row*128 + d8) = v;
  if (l == lens[b]-1) *(u16x8*)(htb + (size_t)b*128 + d8) = v;
}

// ---------------------------------------------------------------------------
// LN + LIF(4 steps, constant input) + alpha = Qs.W3 + masked sum -> a[T,B,D]
// ---------------------------------------------------------------------------
__global__ __launch_bounds__(1024)
void k_attn(const unsigned short* __restrict__ Q0, const unsigned short* __restrict__ htW1,
            const unsigned short* __restrict__ seqh, const int* __restrict__ lens,
            const float* __restrict__ g_q, const float* __restrict__ beta_q,
            const float* __restrict__ W3, float* __restrict__ a_out)
{
  const int b = blockIdx.x, tid = threadIdx.x;
  const int w = tid>>6, lane = tid&63;
  __shared__ float a_acc[16][T_][128];
  for (int i=tid; i<16*T_*128; i+=1024) ((float*)a_acc)[i] = 0.f;
  const float h0 = bf2f(htW1[b*128 + lane]), h1 = bf2f(htW1[b*128 + lane + 64]);
  const float gq0 = g_q[lane], gq1 = g_q[lane+64];
  const float bq0 = beta_q[lane], bq1 = beta_q[lane+64];
  const float w30 = W3[lane], w31 = W3[lane+64];
  const int len = lens[b];
  __syncthreads();
  for (int l = w; l < L_; l += 16) {
    const size_t row = (size_t)b*L_ + l;
    const float q0 = bf2f(Q0[row*128 + lane]) + h0;
    const float q1 = bf2f(Q0[row*128 + lane + 64]) + h1;
    const float m = wsum(q0+q1) * (1.f/128.f);
    const float d0 = q0-m, d1 = q1-m;
    const float var = wsum(d0*d0 + d1*d1) * (1.f/128.f);
    const float inv = rsqrtf(var + 1e-5f);
    const float x0 = d0*inv*gq0 + bq0;
    const float x1 = d1*inv*gq1 + bq1;
    const float sh0 = bf2f(seqh[row*128+lane]), sh1 = bf2f(seqh[row*128+lane+64]);
    const bool active = (l < len);
    float v0=0.f, v1=0.f;
    #pragma unroll
    for (int t=0;t<T_;t++){
      v0 = 0.5f*(v0+x0); v1 = 0.5f*(v1+x1);
      const float s0 = (v0>=1.f)?1.f:0.f, s1 = (v1>=1.f)?1.f:0.f;
      v0 -= s0*v0; v1 -= s1*v1;
      const float alpha = wsum(s0*w30 + s1*w31);
      if (active){ a_acc[w][t][lane] += alpha*sh0; a_acc[w][t][lane+64] += alpha*sh1; }
    }
  }
  __syncthreads();
  for (int i=tid; i<T_*128; i+=1024){
    const int t = i>>7, d = i&127;
    float s = 0.f;
    #pragma unroll
    for (int p=0;p<16;p++) s += a_acc[p][t][d];
    a_out[((size_t)t*B_ + b)*128 + d] = s;
  }
}

// ---------------------------------------------------------------------------
// Final: sh=[a,ht], LIF over T, LN(binary spikes), @Wt.T, mean_T
// ---------------------------------------------------------------------------
__global__ __launch_bounds__(256)
void k_final(const float* __restrict__ a_in, const unsigned short* __restrict__ hidden,
             const int* __restrict__ alias, const int* __restrict__ lens,
             const float* __restrict__ g_sh, const float* __restrict__ beta_sh,
             const float* __restrict__ Wt, float* __restrict__ out)
{
  const int b = blockIdx.x, tid = threadIdx.x;
  const int w = tid>>6, lane = tid&63;
  __shared__ float yl[T_][256];
  __shared__ float part[T_][4];
  const int len = lens[b];
  float xh = 0.f;
  if (tid >= 128) {
    const int al = alias[b*L_ + len - 1];
    xh = bf2f(hidden[((size_t)(b*L_ + al))*128 + (tid-128)]);
  }
  float v = 0.f; float sp[T_];
  #pragma unroll
  for (int t=0;t<T_;t++){
    const float x = (tid<128) ? a_in[((size_t)t*B_ + b)*128 + tid] : xh;
    v = 0.5f*(v + x);
    const float s = (v>=1.f)?1.f:0.f;
    v -= s*v;
    sp[t] = s;
  }
  #pragma unroll
  for (int t=0;t<T_;t++){
    const float r = wsum(sp[t]);
    if (lane==0) part[t][w] = r;
  }
  __syncthreads();
  #pragma unroll
  for (int t=0;t<T_;t++){
    const float k = part[t][0]+part[t][1]+part[t][2]+part[t][3];
    const float mean = k * (1.f/256.f);
    const float varr = mean - mean*mean;   // spikes binary: E[x^2]=E[x]
    const float inv = rsqrtf(varr + 1e-5f);
    yl[t][tid] = (sp[t]-mean)*inv*g_sh[tid] + beta_sh[tid];
  }
  __syncthreads();
  if (tid < 128) {
    float acc = 0.f;
    const float* wrp = Wt + (size_t)tid*256;
    for (int k=0;k<256;k++)
      acc += wrp[k]*(yl[0][k]+yl[1][k]+yl[2][k]+yl[3][k]);
    out[(size_t)b*128 + tid] = acc*0.25f;
  }
}

// ---------------------------------------------------------------------------
extern "C" void kernel_launch(void* const* d_in, const int* in_sizes, int n_in,
                              void* d_out, int out_size, void* d_ws, size_t ws_size,
                              hipStream_t stream)
{
  const int*   alias  = (const int*)d_in[1];
  const int*   items  = (const int*)d_in[2];
  const int*   lens   = (const int*)d_in[4];
  const float* emb    = (const float*)d_in[5];
  const float* W_in   = (const float*)d_in[6];
  const float* b_in   = (const float*)d_in[7];
  const float* W_out  = (const float*)d_in[8];
  const float* b_out  = (const float*)d_in[9];
  const float* w_ih   = (const float*)d_in[10];
  const float* w_hh   = (const float*)d_in[11];
  const float* b_ih   = (const float*)d_in[12];
  const float* b_hh   = (const float*)d_in[13];
  const float* b_iah  = (const float*)d_in[14];
  const float* b_ioh  = (const float*)d_in[15];
  const float* W1     = (const float*)d_in[16];
  const float* W2     = (const float*)d_in[17];
  const float* W3     = (const float*)d_in[18];
  const float* Wt     = (const float*)d_in[19];
  const float* g_q    = (const float*)d_in[20];
  const float* beta_q = (const float*)d_in[21];
  const float* g_sh   = (const float*)d_in[22];
  const float* beta_sh= (const float*)d_in[23];

  char* ws = (char*)d_ws;
  size_t off = 0;
  auto alloc = [&](size_t bytes)->void* {
    void* p = ws + off; off += (bytes + 255) & ~(size_t)255; return p;
  };
  unsigned short* X3    = (unsigned short*)alloc((size_t)M_*384*2);   // [aggIn|aggOut|h]
  unsigned short* hidden= (unsigned short*)alloc((size_t)M_*128*2);
  unsigned short* seqh  = (unsigned short*)alloc((size_t)M_*128*2);
  unsigned short* Q0    = (unsigned short*)alloc((size_t)M_*128*2);
  unsigned short* htb   = (unsigned short*)alloc((size_t)B_*128*2);
  unsigned short* htW1  = (unsigned short*)alloc((size_t)B_*128*2);
  float*          a_buf = (float*)alloc((size_t)T_*B_*128*4);
  unsigned short* Wbig  = (unsigned short*)alloc((size_t)512*384*2);
  unsigned short* w1b   = (unsigned short*)alloc(16384*2);
  unsigned short* w2b   = (unsigned short*)alloc(16384*2);
  float*          biasBase = (float*)alloc(512*4);
  float*          uIn   = (float*)alloc(512*4);
  float*          uOut  = (float*)alloc(512*4);
  unsigned char*  cf    = (unsigned char*)alloc(M_);
  if (off > ws_size) return;

  k_prepW<<<512,128,0,stream>>>(w_ih,w_hh,W_in,W_out,b_in,b_out,b_ih,b_hh,
                                b_iah,b_ioh,Wbig,biasBase,uIn,uOut);
  k_prepSmall<<<64,256,0,stream>>>(W1,W2,w1b,w2b);
  k_aggemb<<<B_,1024,0,stream>>>(alias, items, lens, emb, X3, cf);
  k_gates_gru<<<dim3(2,800),512,0,stream>>>(X3, Wbig, biasBase, uIn, uOut, cf, hidden);
  k_gather<<<M_*16/256,256,0,stream>>>(hidden, alias, lens, seqh, htb);
  gemm_bt<<<dim3(1,4),256,0,stream>>>(htb, 128, w1b, 128, nullptr, htW1, 128, 128);
  gemm_bt<<<dim3(1,800),256,0,stream>>>(seqh, 128, w2b, 128, nullptr, Q0, 128, 128);
  k_attn<<<B_,1024,0,stream>>>(Q0, htW1, seqh, lens, g_q, beta_q, W3, a_buf);
  k_final<<<B_,256,0,stream>>>(a_buf, hidden, alias, lens, g_sh, beta_sh, Wt, (float*)d_out);
}

// Round 5
// 199.599 us; speedup vs baseline: 2.2239x; 1.1451x over previous
//
#include <hip/hip_runtime.h>
#include <hip/hip_bf16.h>
#include <cstdint>
#include <cstddef>

#define B_ 512
#define L_ 200
#define D_ 128
#define M_ (B_*L_)
#define T_ 4

typedef short bf16x8 __attribute__((ext_vector_type(8)));
typedef unsigned short u16x8 __attribute__((ext_vector_type(8)));
typedef float f32x4 __attribute__((ext_vector_type(4)));

__device__ __forceinline__ float bf2f(unsigned short u){
  union { unsigned int i; float f; } c; c.i = ((unsigned int)u)<<16; return c.f;
}
__device__ __forceinline__ unsigned short f2bf(float f){
  union { float f; unsigned int i; } c; c.f = f;
  unsigned int r = c.i + 0x7FFFu + ((c.i>>16)&1u);
  return (unsigned short)(r>>16);
}
__device__ __forceinline__ float wsum(float v){
  #pragma unroll
  for (int m=1;m<64;m<<=1) v += __shfl_xor(v, m, 64);
  return v;
}
__device__ __forceinline__ void gload_lds16(const void* g, void* l){
  __builtin_amdgcn_global_load_lds(
      (const __attribute__((address_space(1))) void*)g,
      (__attribute__((address_space(3))) void*)l, 16, 0, 0);
}

// ---------------------------------------------------------------------------
// bf16 GEMM, C[M,N] = A[M,K] @ Bt[N,K]^T + bias. 128x128 tile, BK=32,
// 4 waves, 16x16x32 MFMA, slot-swizzled LDS, 2-phase double-buffered staging
// (stage t+1 issued before compute of t; one drain+barrier per K-step).
// mlimit: optional compact row count -> early-exit blocks past it.
// ---------------------------------------------------------------------------
__global__ __launch_bounds__(256)
void gemm_bt(const unsigned short* __restrict__ A, int lda,
             const unsigned short* __restrict__ Bt, int ldb,
             const float* __restrict__ bias,
             unsigned short* __restrict__ C, int ldc, int K,
             const int* __restrict__ mlimit)
{
  const int m0 = blockIdx.y * 128;
  if (mlimit && m0 >= *mlimit) return;
  __shared__ __align__(16) short sAs[2][128*32];
  __shared__ __align__(16) short sBs[2][128*32];
  const int tid = threadIdx.x;
  const int n0 = blockIdx.x * 128;
  const int lane = tid & 63;
  const int w = tid >> 6;
  const int wr = (w>>1)*64, wc = (w&1)*64;

  f32x4 acc[4][4];
  #pragma unroll
  for (int i=0;i<4;i++)
    #pragma unroll
    for (int j=0;j<4;j++) acc[i][j] = (f32x4){0.f,0.f,0.f,0.f};

  const int c1 = tid, c2 = tid + 256;
  const int r1 = c1>>2, s1 = c1&3, k1 = ((s1 ^ ((r1>>1)&3))&3)<<3;
  const int r2 = c2>>2, s2 = c2&3, k2 = ((s2 ^ ((r2>>1)&3))&3)<<3;
  const int fr = lane & 15;
  const int fq = lane >> 4;
  const int fk = ((fq ^ ((fr>>1)&3))&3)<<3;

  auto stage = [&](int t){
    const int buf = t & 1, ks = t << 5;
    gload_lds16(A  + (size_t)(m0 + r1)*lda + ks + k1, sAs[buf] + (size_t)c1*8);
    gload_lds16(A  + (size_t)(m0 + r2)*lda + ks + k2, sAs[buf] + (size_t)c2*8);
    gload_lds16(Bt + (size_t)(n0 + r1)*ldb + ks + k1, sBs[buf] + (size_t)c1*8);
    gload_lds16(Bt + (size_t)(n0 + r2)*ldb + ks + k2, sBs[buf] + (size_t)c2*8);
  };
  const int nT = K >> 5;
  stage(0);
  __syncthreads();
  for (int t=0; t<nT; ++t){
    if (t+1 < nT) stage(t+1);
    const short* a_ = sAs[t&1];
    const short* b_ = sBs[t&1];
    bf16x8 af[4], bfr[4];
    #pragma unroll
    for (int i=0;i<4;i++){
      af[i]  = *(const bf16x8*)(a_ + (wr + i*16 + fr)*32 + fk);
      bfr[i] = *(const bf16x8*)(b_ + (wc + i*16 + fr)*32 + fk);
    }
    #pragma unroll
    for (int i=0;i<4;i++)
      #pragma unroll
      for (int j=0;j<4;j++)
        acc[i][j] = __builtin_amdgcn_mfma_f32_16x16x32_bf16(af[i], bfr[j], acc[i][j], 0,0,0);
    __syncthreads();
  }

  const int orow = fq<<2;
  #pragma unroll
  for (int i=0;i<4;i++){
    #pragma unroll
    for (int j=0;j<4;j++){
      const int gn = n0 + wc + j*16 + fr;
      const float bv = bias ? bias[gn] : 0.f;
      #pragma unroll
      for (int v=0;v<4;v++){
        const int gm = m0 + wr + i*16 + orow + v;
        C[(size_t)gm*ldc + gn] = f2bf(acc[i][j][v] + bv);
      }
    }
  }
}

// ---------------------------------------------------------------------------
// Weight prep: Wbig[512][384] gate-interleaved (p = dim*4+g), see R4.
// ---------------------------------------------------------------------------
__global__ __launch_bounds__(128)
void k_prepW(const float* __restrict__ w_ih, const float* __restrict__ w_hh,
             const float* __restrict__ W_in, const float* __restrict__ W_out,
             const float* __restrict__ b_in, const float* __restrict__ b_out,
             const float* __restrict__ b_ih, const float* __restrict__ b_hh,
             const float* __restrict__ b_iah, const float* __restrict__ b_ioh,
             unsigned short* __restrict__ Wbig, float* __restrict__ biasBase,
             float* __restrict__ uIn, float* __restrict__ uOut)
{
  const int p = blockIdx.x, t = threadIdx.x;
  const int dim = p>>2, g = p&3;
  const int row = (g==0) ? dim : (g==1) ? 128+dim : 256+dim;
  const bool has_ih = (g!=3), has_hh = (g!=2);
  __shared__ float wl[128], wrg[128], red[3][128];
  wl[t]  = has_ih ? w_ih[(size_t)row*256 + t]       : 0.f;
  wrg[t] = has_ih ? w_ih[(size_t)row*256 + 128 + t] : 0.f;
  __syncthreads();
  float cin = 0.f, cout = 0.f;
  if (has_ih) {
    for (int m=0;m<128;m++){
      cin  += wl[m]  * W_in [m*128 + t];
      cout += wrg[m] * W_out[m*128 + t];
    }
  }
  Wbig[(size_t)p*384 +       t] = f2bf(cin);
  Wbig[(size_t)p*384 + 128 + t] = f2bf(cout);
  Wbig[(size_t)p*384 + 256 + t] = f2bf(has_hh ? w_hh[(size_t)row*128 + t] : 0.f);
  red[0][t] = wl[t]*b_iah[t] + wrg[t]*b_ioh[t];
  red[1][t] = wl[t]*b_in[t];
  red[2][t] = wrg[t]*b_out[t];
  __syncthreads();
  if (t == 0) {
    float v=0.f, ui=0.f, uo=0.f;
    for (int k=0;k<128;k++){ v += red[0][k]; ui += red[1][k]; uo += red[2][k]; }
    float bb;
    if (g==0)      bb = b_ih[dim]     + b_hh[dim]     + v;
    else if (g==1) bb = b_ih[128+dim] + b_hh[128+dim] + v;
    else if (g==2) bb = b_ih[256+dim] + v;
    else           bb = b_hh[256+dim];
    biasBase[p] = bb;
    uIn[p]  = has_ih ? ui : 0.f;
    uOut[p] = has_ih ? uo : 0.f;
  }
}

__global__ __launch_bounds__(256)
void k_prepSmall(const float* __restrict__ W1, const float* __restrict__ W2,
                 unsigned short* __restrict__ w1b, unsigned short* __restrict__ w2b)
{
  const int i = blockIdx.x*256 + threadIdx.x;
  if (i < 16384) { w1b[i] = f2bf(W1[i]); w2b[i] = f2bf(W2[i]); }
}

// ---------------------------------------------------------------------------
// Per-batch node count: nb[b] = max(alias[b, 0:len]) + 1
// ---------------------------------------------------------------------------
__global__ __launch_bounds__(64)
void k_nb(const int* __restrict__ alias, const int* __restrict__ lens,
          int* __restrict__ nb)
{
  const int b = blockIdx.x, lane = threadIdx.x;
  const int len = lens[b];
  int m = 0;
  for (int l=lane; l<len; l+=64) m = max(m, alias[b*L_ + l]);
  #pragma unroll
  for (int o=1;o<64;o<<=1) m = max(m, __shfl_xor(m, o, 64));
  if (lane==0) nb[b] = m + 1;
}

// ---------------------------------------------------------------------------
// Exclusive prefix sums of nb and len -> nbase[513], vbase[513]
// ---------------------------------------------------------------------------
__global__ __launch_bounds__(512)
void k_scan(const int* __restrict__ nb, const int* __restrict__ lens,
            int* __restrict__ nbase, int* __restrict__ vbase)
{
  __shared__ int A[2][512], Bv[2][512];
  const int t = threadIdx.x;
  const int a0 = nb[t], b0 = lens[t];
  A[0][t] = a0; Bv[0][t] = b0;
  __syncthreads();
  int cur = 0;
  for (int off=1; off<512; off<<=1){
    const int nxt = cur^1;
    A[nxt][t]  = A[cur][t]  + (t>=off ? A[cur][t-off]  : 0);
    Bv[nxt][t] = Bv[cur][t] + (t>=off ? Bv[cur][t-off] : 0);
    __syncthreads();
    cur = nxt;
  }
  nbase[t] = A[cur][t] - a0;
  vbase[t] = Bv[cur][t] - b0;
  if (t==511){ nbase[512] = A[cur][511]; vbase[512] = Bv[cur][511]; }
}

// ---------------------------------------------------------------------------
// Fused embedding gather + graph aggregation -> COMPACT X3 rows [nbase[b]+j].
// Only j < nb[b] node rows are produced (the only ones ever gathered).
// ---------------------------------------------------------------------------
__global__ __launch_bounds__(1024)
void k_aggemb(const int* __restrict__ alias, const int* __restrict__ items,
              const int* __restrict__ lens, const float* __restrict__ emb,
              const int* __restrict__ nb, const int* __restrict__ nbase,
              unsigned short* __restrict__ X3, unsigned char* __restrict__ cf)
{
  const int b = blockIdx.x, tid = threadIdx.x;
  __shared__ unsigned short hl[L_*128];        // 50KB
  __shared__ int al[L_], it[L_];
  __shared__ unsigned bmIn[L_*8], bmOut[L_*8]; // 12.8KB
  if (tid < L_) { al[tid] = alias[b*L_ + tid]; it[tid] = items[b*L_ + tid]; }
  for (int i=tid; i<L_*8; i+=1024){ bmIn[i]=0u; bmOut[i]=0u; }
  __syncthreads();
  const int len = lens[b], nB = nb[b], base = nbase[b];
  if (tid < len-1) {
    const int r = al[tid], c = al[tid+1];
    atomicOr(&bmIn[c*8 + (r>>5)],  1u<<(r&31));
    atomicOr(&bmOut[r*8 + (c>>5)], 1u<<(c&31));
  }
  const int rr = tid>>5, cc = (tid&31)<<2;
  for (int s=0; s<nB; s+=32) {
    const int j = s + rr;
    if (j < nB) {
      const float4 v = *(const float4*)(emb + (size_t)it[j]*128 + cc);
      ushort4 o; o.x=f2bf(v.x); o.y=f2bf(v.y); o.z=f2bf(v.z); o.w=f2bf(v.w);
      *(ushort4*)(hl + j*128 + cc) = o;
      *(ushort4*)(X3 + (size_t)(base + j)*384 + 256 + cc) = o;
    }
  }
  __syncthreads();
  const int g = tid >> 7, d = tid & 127;
  for (int s=0; s<nB; s+=8) {
    const int i = s + g;
    if (i < nB) {
      float si=0.f, so=0.f; int ci=0, co=0;
      #pragma unroll
      for (int wd=0; wd<8; ++wd) {
        unsigned word = bmIn[i*8+wd];
        while (word) { int j = __ffs(word)-1; word &= word-1u;
          si += bf2f(hl[(wd*32+j)*128 + d]); ci++; }
        word = bmOut[i*8+wd];
        while (word) { int j = __ffs(word)-1; word &= word-1u;
          so += bf2f(hl[(wd*32+j)*128 + d]); co++; }
      }
      unsigned short* xr = X3 + (size_t)(base + i)*384;
      xr[d]       = f2bf(si / (float)(ci>0?ci:1));
      xr[128 + d] = f2bf(so / (float)(co>0?co:1));
      if (d == 0) cf[base + i] = (unsigned char)((ci>0?1:0) | (co>0?2:0));
    }
  }
}

// ---------------------------------------------------------------------------
// Fused gates GEMM + GRU over COMPACT rows, register-only epilogue,
// 2-phase double-buffered staging. Early-exit past mlimit (=Mc).
// ---------------------------------------------------------------------------
__global__ __launch_bounds__(512)
void k_gates_gru(const unsigned short* __restrict__ X3,
                 const unsigned short* __restrict__ Wbig,
                 const float* __restrict__ biasBase,
                 const float* __restrict__ uIn,
                 const float* __restrict__ uOut,
                 const unsigned char* __restrict__ cf,
                 unsigned short* __restrict__ hidden,
                 const int* __restrict__ mlimit)
{
  const int m0 = blockIdx.y * 128;
  if (m0 >= *mlimit) return;
  __shared__ __align__(16) short sA[2][128*32];   // 16KB
  __shared__ __align__(16) short sB[2][256*32];   // 32KB
  const int tid = threadIdx.x;
  const int p0 = blockIdx.x * 256;
  const int lane = tid & 63;
  const int w = tid >> 6;
  const int wr  = (w>>2)*64;
  const int wcp = (w&3)*64;
  const int fr = lane & 15;
  const int fq = lane >> 4;
  const int fk = ((fq ^ ((fr>>1)&3))&3)<<3;

  f32x4 acc[4][4];
  #pragma unroll
  for (int i=0;i<4;i++)
    #pragma unroll
    for (int j=0;j<4;j++) acc[i][j] = (f32x4){0.f,0.f,0.f,0.f};

  const int ra = tid>>2, sa_ = tid&3, ka = ((sa_ ^ ((ra>>1)&3))&3)<<3;
  const int c1 = tid + 512, rb1 = c1>>2, sb1 = c1&3, kb1 = ((sb1 ^ ((rb1>>1)&3))&3)<<3;

  auto stage = [&](int t){
    const int buf = t & 1, ks = t << 5;
    gload_lds16(X3   + (size_t)(m0 + ra )*384 + ks + ka , sA[buf] + (size_t)tid*8);
    gload_lds16(Wbig + (size_t)(p0 + ra )*384 + ks + ka , sB[buf] + (size_t)tid*8);
    gload_lds16(Wbig + (size_t)(p0 + rb1)*384 + ks + kb1, sB[buf] + (size_t)(c1-512)*8 + 512*8);
  };
  stage(0);
  __syncthreads();
  for (int t=0; t<12; ++t){
    if (t < 11) stage(t+1);
    const short* a_ = sA[t&1];
    const short* b_ = sB[t&1];
    bf16x8 af[4], bfr[4];
    #pragma unroll
    for (int i=0;i<4;i++){
      af[i]  = *(const bf16x8*)(a_ + (wr  + i*16 + fr)*32 + fk);
      bfr[i] = *(const bf16x8*)(b_ + (wcp + i*16 + fr)*32 + fk);
    }
    #pragma unroll
    for (int i=0;i<4;i++)
      #pragma unroll
      for (int j=0;j<4;j++)
        acc[i][j] = __builtin_amdgcn_mfma_f32_16x16x32_bf16(af[i], bfr[j], acc[i][j], 0,0,0);
    __syncthreads();
  }

  // Epilogue: 4x4 quad transpose -> all gates in one lane -> GRU -> hidden.
  const bool q0b = (lane & 1), q1b = (lane & 2);
  #pragma unroll
  for (int j=0;j<4;j++){
    const int dim = (p0>>2) + (w&3)*16 + j*4 + ((lane>>2)&3);
    const float4 bb = *(const float4*)(biasBase + dim*4);
    const float4 bi = *(const float4*)(uIn  + dim*4);
    const float4 bo = *(const float4*)(uOut + dim*4);
    #pragma unroll
    for (int i=0;i<4;i++){
      const float a0=acc[i][j][0], a1=acc[i][j][1], a2=acc[i][j][2], a3=acc[i][j][3];
      const float t0=__shfl_xor(a0,1), t1=__shfl_xor(a1,1), t2=__shfl_xor(a2,1), t3=__shfl_xor(a3,1);
      const float s0 = q0b? t1:a0, s1 = q0b? a1:t0, s2 = q0b? t3:a2, s3 = q0b? a3:t2;
      const float u0=__shfl_xor(s0,2), u1=__shfl_xor(s1,2), u2=__shfl_xor(s2,2), u3=__shfl_xor(s3,2);
      float G0 = q1b? u2:s0, G1 = q1b? u3:s1, G2 = q1b? s2:u0, G3 = q1b? s3:u1;
      const int row = m0 + wr + i*16 + fq*4 + (lane&3);
      const unsigned c = cf[row];
      const float fi = (c&1) ? 1.f : 0.f, fo = (c&2) ? 1.f : 0.f;
      G0 += bb.x + fi*bi.x + fo*bo.x;
      G1 += bb.y + fi*bi.y + fo*bo.y;
      G2 += bb.z + fi*bi.z + fo*bo.z;
      G3 += bb.w;
      const float h = bf2f(X3[(size_t)row*384 + 256 + dim]);
      const float r = 1.f/(1.f+__expf(-G0));
      const float z = 1.f/(1.f+__expf(-G1));
      const float x = G2 + r*G3;
      const float n = 1.f - 2.f/(__expf(2.f*x)+1.f);   // tanh
      hidden[(size_t)row*128 + dim] = f2bf((1.f-z)*h + z*n);
    }
  }
}

// ---------------------------------------------------------------------------
// seq_hidden gather (compact) + ht extraction. Valid rows l < len only.
// ---------------------------------------------------------------------------
__global__ __launch_bounds__(256)
void k_gather(const unsigned short* __restrict__ hidden,
              const int* __restrict__ alias, const int* __restrict__ lens,
              const int* __restrict__ nbase, const int* __restrict__ vbase,
              unsigned short* __restrict__ seqv, unsigned short* __restrict__ htb)
{
  const int idx = blockIdx.x*256 + threadIdx.x;  // M*16
  const int row = idx >> 4, d8 = (idx & 15) << 3;
  const int b = row / L_, l = row - b*L_;
  const int len = lens[b];
  if (l >= len) return;
  u16x8 v = *(const u16x8*)(hidden + (size_t)(nbase[b] + alias[row])*128 + d8);
  *(u16x8*)(seqv + (size_t)(vbase[b] + l)*128 + d8) = v;
  if (l == len-1) *(u16x8*)(htb + (size_t)b*128 + d8) = v;
}

// ---------------------------------------------------------------------------
// LN + LIF + alpha + masked sum over compact valid rows -> a[T,B,D]
// ---------------------------------------------------------------------------
__global__ __launch_bounds__(1024)
void k_attn(const unsigned short* __restrict__ Q0, const unsigned short* __restrict__ htW1,
            const unsigned short* __restrict__ seqv, const int* __restrict__ lens,
            const int* __restrict__ vbase,
            const float* __restrict__ g_q, const float* __restrict__ beta_q,
            const float* __restrict__ W3, float* __restrict__ a_out)
{
  const int b = blockIdx.x, tid = threadIdx.x;
  const int w = tid>>6, lane = tid&63;
  __shared__ float a_acc[16][T_][128];
  for (int i=tid; i<16*T_*128; i+=1024) ((float*)a_acc)[i] = 0.f;
  const float h0 = bf2f(htW1[b*128 + lane]), h1 = bf2f(htW1[b*128 + lane + 64]);
  const float gq0 = g_q[lane], gq1 = g_q[lane+64];
  const float bq0 = beta_q[lane], bq1 = beta_q[lane+64];
  const float w30 = W3[lane], w31 = W3[lane+64];
  const int len = lens[b], vb = vbase[b];
  __syncthreads();
  for (int l = w; l < len; l += 16) {
    const size_t row = (size_t)(vb + l);
    const float q0 = bf2f(Q0[row*128 + lane]) + h0;
    const float q1 = bf2f(Q0[row*128 + lane + 64]) + h1;
    const float m = wsum(q0+q1) * (1.f/128.f);
    const float d0 = q0-m, d1 = q1-m;
    const float var = wsum(d0*d0 + d1*d1) * (1.f/128.f);
    const float inv = rsqrtf(var + 1e-5f);
    const float x0 = d0*inv*gq0 + bq0;
    const float x1 = d1*inv*gq1 + bq1;
    const float sh0 = bf2f(seqv[row*128+lane]), sh1 = bf2f(seqv[row*128+lane+64]);
    float v0=0.f, v1=0.f;
    #pragma unroll
    for (int t=0;t<T_;t++){
      v0 = 0.5f*(v0+x0); v1 = 0.5f*(v1+x1);
      const float s0 = (v0>=1.f)?1.f:0.f, s1 = (v1>=1.f)?1.f:0.f;
      v0 -= s0*v0; v1 -= s1*v1;
      const float alpha = wsum(s0*w30 + s1*w31);
      a_acc[w][t][lane] += alpha*sh0; a_acc[w][t][lane+64] += alpha*sh1;
    }
  }
  __syncthreads();
  for (int i=tid; i<T_*128; i+=1024){
    const int t = i>>7, d = i&127;
    float s = 0.f;
    #pragma unroll
    for (int p=0;p<16;p++) s += a_acc[p][t][d];
    a_out[((size_t)t*B_ + b)*128 + d] = s;
  }
}

// ---------------------------------------------------------------------------
// Final: sh=[a,ht], LIF over T, LN(binary spikes), @Wt.T, mean_T
// ---------------------------------------------------------------------------
__global__ __launch_bounds__(256)
void k_final(const float* __restrict__ a_in, const unsigned short* __restrict__ hidden,
             const int* __restrict__ alias, const int* __restrict__ lens,
             const int* __restrict__ nbase,
             const float* __restrict__ g_sh, const float* __restrict__ beta_sh,
             const float* __restrict__ Wt, float* __restrict__ out)
{
  const int b = blockIdx.x, tid = threadIdx.x;
  const int w = tid>>6, lane = tid&63;
  __shared__ float ys[256];
  __shared__ float part[T_][4];
  const int len = lens[b];
  float xh = 0.f;
  if (tid >= 128) {
    const int al = alias[b*L_ + len - 1];
    xh = bf2f(hidden[((size_t)(nbase[b] + al))*128 + (tid-128)]);
  }
  float v = 0.f; float sp[T_];
  #pragma unroll
  for (int t=0;t<T_;t++){
    const float x = (tid<128) ? a_in[((size_t)t*B_ + b)*128 + tid] : xh;
    v = 0.5f*(v + x);
    const float s = (v>=1.f)?1.f:0.f;
    v -= s*v;
    sp[t] = s;
  }
  #pragma unroll
  for (int t=0;t<T_;t++){
    const float r = wsum(sp[t]);
    if (lane==0) part[t][w] = r;
  }
  __syncthreads();
  float acc4 = 0.f;
  #pragma unroll
  for (int t=0;t<T_;t++){
    const float k = part[t][0]+part[t][1]+part[t][2]+part[t][3];
    const float mean = k * (1.f/256.f);
    const float varr = mean - mean*mean;   // spikes binary: E[x^2]=E[x]
    const float inv = rsqrtf(varr + 1e-5f);
    acc4 += (sp[t]-mean)*inv;
  }
  ys[tid] = acc4*g_sh[tid] + 4.f*beta_sh[tid];   // sum over t of LN rows
  __syncthreads();
  if (tid < 128) {
    float acc = 0.f;
    const float4* wr4 = (const float4*)(Wt + (size_t)tid*256);
    const float4* ys4 = (const float4*)ys;
    #pragma unroll 8
    for (int k=0;k<64;k++){
      const float4 wv = wr4[k], yv = ys4[k];
      acc += wv.x*yv.x + wv.y*yv.y + wv.z*yv.z + wv.w*yv.w;
    }
    out[(size_t)b*128 + tid] = acc*0.25f;
  }
}

// ---------------------------------------------------------------------------
extern "C" void kernel_launch(void* const* d_in, const int* in_sizes, int n_in,
                              void* d_out, int out_size, void* d_ws, size_t ws_size,
                              hipStream_t stream)
{
  const int*   alias  = (const int*)d_in[1];
  const int*   items  = (const int*)d_in[2];
  const int*   lens   = (const int*)d_in[4];
  const float* emb    = (const float*)d_in[5];
  const float* W_in   = (const float*)d_in[6];
  const float* b_in   = (const float*)d_in[7];
  const float* W_out  = (const float*)d_in[8];
  const float* b_out  = (const float*)d_in[9];
  const float* w_ih   = (const float*)d_in[10];
  const float* w_hh   = (const float*)d_in[11];
  const float* b_ih   = (const float*)d_in[12];
  const float* b_hh   = (const float*)d_in[13];
  const float* b_iah  = (const float*)d_in[14];
  const float* b_ioh  = (const float*)d_in[15];
  const float* W1     = (const float*)d_in[16];
  const float* W2     = (const float*)d_in[17];
  const float* W3     = (const float*)d_in[18];
  const float* Wt     = (const float*)d_in[19];
  const float* g_q    = (const float*)d_in[20];
  const float* beta_q = (const float*)d_in[21];
  const float* g_sh   = (const float*)d_in[22];
  const float* beta_sh= (const float*)d_in[23];

  char* ws = (char*)d_ws;
  size_t off = 0;
  auto alloc = [&](size_t bytes)->void* {
    void* p = ws + off; off += (bytes + 255) & ~(size_t)255; return p;
  };
  unsigned short* X3    = (unsigned short*)alloc((size_t)M_*384*2);   // compact
  unsigned short* hidden= (unsigned short*)alloc((size_t)M_*128*2);   // compact
  unsigned short* seqv  = (unsigned short*)alloc((size_t)M_*128*2);   // compact
  unsigned short* Q0c   = (unsigned short*)alloc((size_t)M_*128*2);   // compact
  unsigned short* htb   = (unsigned short*)alloc((size_t)B_*128*2);
  unsigned short* htW1  = (unsigned short*)alloc((size_t)B_*128*2);
  float*          a_buf = (float*)alloc((size_t)T_*B_*128*4);
  unsigned short* Wbig  = (unsigned short*)alloc((size_t)512*384*2);
  unsigned short* w1b   = (unsigned short*)alloc(16384*2);
  unsigned short* w2b   = (unsigned short*)alloc(16384*2);
  float*          biasBase = (float*)alloc(512*4);
  float*          uIn   = (float*)alloc(512*4);
  float*          uOut  = (float*)alloc(512*4);
  unsigned char*  cf    = (unsigned char*)alloc(M_);
  int*            nb    = (int*)alloc(512*4);
  int*            nbase = (int*)alloc(513*4);
  int*            vbase = (int*)alloc(513*4);
  if (off > ws_size) return;

  k_prepW<<<512,128,0,stream>>>(w_ih,w_hh,W_in,W_out,b_in,b_out,b_ih,b_hh,
                                b_iah,b_ioh,Wbig,biasBase,uIn,uOut);
  k_prepSmall<<<64,256,0,stream>>>(W1,W2,w1b,w2b);
  k_nb<<<B_,64,0,stream>>>(alias, lens, nb);
  k_scan<<<1,512,0,stream>>>(nb, lens, nbase, vbase);
  k_aggemb<<<B_,1024,0,stream>>>(alias, items, lens, emb, nb, nbase, X3, cf);
  k_gates_gru<<<dim3(2,800),512,0,stream>>>(X3, Wbig, biasBase, uIn, uOut, cf,
                                            hidden, nbase+512);
  k_gather<<<M_*16/256,256,0,stream>>>(hidden, alias, lens, nbase, vbase, seqv, htb);
  gemm_bt<<<dim3(1,4),256,0,stream>>>(htb, 128, w1b, 128, nullptr, htW1, 128, 128, nullptr);
  gemm_bt<<<dim3(1,800),256,0,stream>>>(seqv, 128, w2b, 128, nullptr, Q0c, 128, 128, vbase+512);
  k_attn<<<B_,1024,0,stream>>>(Q0c, htW1, seqv, lens, vbase, g_q, beta_q, W3, a_buf);
  k_final<<<B_,256,0,stream>>>(a_buf, hidden, alias, lens, nbase, g_sh, beta_sh, Wt, (float*)d_out);
}